// Round 13
// baseline (122.444 us; speedup 1.0000x reference)
//
#include <hip/hip_runtime.h>
#include <hip/hip_bf16.h>

#define NROW 8192   // B*A = 64*128
#define INC  128
#define OUTC 64
#define BG   16     // key-split factor

// Q is pre-scaled by log2(e)/sqrt(64) at projection time, so attention
// computes p = exp2(q'.k) with a single v_exp_f32 per score.
#define QSCALE 0.18033688011112042f

typedef __bf16 bf16x8 __attribute__((ext_vector_type(8)));
typedef __bf16 bf16x4 __attribute__((ext_vector_type(4)));
typedef short  s16x4  __attribute__((ext_vector_type(4)));
typedef short  s16x8  __attribute__((ext_vector_type(8)));
typedef float  f32x4  __attribute__((ext_vector_type(4)));

static __device__ __forceinline__ f32x4 mfma16(bf16x8 a, bf16x8 b, f32x4 c) {
    return __builtin_amdgcn_mfma_f32_16x16x32_bf16(a, b, c, 0, 0, 0);
}
// 16x16x16 bf16 (K=16). C/D of S^T IS the A-operand layout of P for PV.
static __device__ __forceinline__ f32x4 mfma1k(s16x4 a, s16x4 b, f32x4 c) {
    return __builtin_amdgcn_mfma_f32_16x16x16bf16_1k(a, b, c, 0, 0, 0);
}

static __device__ __forceinline__ bf16x8 cvt8(float4 lo, float4 hi) {
    bf16x8 r;
    r[0] = (__bf16)lo.x; r[1] = (__bf16)lo.y; r[2] = (__bf16)lo.z; r[3] = (__bf16)lo.w;
    r[4] = (__bf16)hi.x; r[5] = (__bf16)hi.y; r[6] = (__bf16)hi.z; r[7] = (__bf16)hi.w;
    return r;
}
static __device__ __forceinline__ s16x4 vlo(s16x8 x) {
    return __builtin_shufflevector(x, x, 0, 1, 2, 3);
}
static __device__ __forceinline__ s16x4 vhi(s16x8 x) {
    return __builtin_shufflevector(x, x, 4, 5, 6, 7);
}

// ---------------------------------------------------------------------------
// Kernel 1: projection via MFMA. grid = 256 = b(64) x aq(4), 1 block/CU.
// Slab staged once; 12 n-tiles (3 mats x 4) spread 3-per-wave. qbf is
// frag-tiled + pre-scaled; kbf/vbf fragment-linear (attn LDS staging is a
// linear tid*16 copy, ds_read_b128 conflict-free); vnb row-major normalized.
__global__ __launch_bounds__(256) void proj_kernel(
    const float* __restrict__ feat,
    const float* __restrict__ Wq, const float* __restrict__ bq,
    const float* __restrict__ Wk, const float* __restrict__ bk,
    const float* __restrict__ Wv, const float* __restrict__ bv,
    __hip_bfloat16* __restrict__ qbf, __hip_bfloat16* __restrict__ kbf,
    __hip_bfloat16* __restrict__ vbf, __hip_bfloat16* __restrict__ vnb)
{
    __shared__ float slab[32 * 132];
    __shared__ float vbuf[32 * 66];
    __shared__ float invb[32];

    const int tid = threadIdx.x;
    const int w    = tid >> 6;
    const int lane = tid & 63;
    const int l16  = lane & 15;
    const int quad = lane >> 4;

    const int b   = blockIdx.x >> 2;
    const int a0  = (blockIdx.x & 3) * 32;
    const int r0  = b * 128 + a0;
    const float* fb = feat + (size_t)b * INC * 128;

    for (int i = tid; i < 32 * 128; i += 256) {
        int c = i >> 5, a = i & 31;
        slab[a * 132 + c] = fb[c * 128 + a0 + a];
    }
    __syncthreads();

    f32x4 acc[3][2];
    #pragma unroll
    for (int t = 0; t < 3; ++t)
        #pragma unroll
        for (int u = 0; u < 2; ++u)
            acc[t][u] = (f32x4){0.f, 0.f, 0.f, 0.f};

    #pragma unroll
    for (int kc = 0; kc < 4; ++kc) {
        const int k0 = kc * 32 + quad * 8;
        bf16x8 afr[2];
        #pragma unroll
        for (int u = 0; u < 2; ++u) {
            const float* ar = slab + (u * 16 + l16) * 132 + k0;
            afr[u] = cvt8(*(const float4*)ar, *(const float4*)(ar + 4));
        }
        #pragma unroll
        for (int t = 0; t < 3; ++t) {
            const int tile = w * 3 + t;
            const int mat  = tile >> 2;
            const float* W = (mat == 0) ? Wq : (mat == 1) ? Wk : Wv;
            const float* wr = W + ((tile & 3) * 16 + l16) * INC + k0;
            bf16x8 bfr = cvt8(*(const float4*)wr, *(const float4*)(wr + 4));
            #pragma unroll
            for (int u = 0; u < 2; ++u)
                acc[t][u] = mfma16(afr[u], bfr, acc[t][u]);
        }
    }

    #pragma unroll
    for (int t = 0; t < 3; ++t) {
        const int tile = w * 3 + t;
        const int mat  = tile >> 2;
        const int nt   = tile & 3;
        const float* bias = (mat == 0) ? bq : (mat == 1) ? bk : bv;
        const float bl = bias[nt * 16 + l16];
        if (mat == 0) {
            #pragma unroll
            for (int u = 0; u < 2; ++u) {
                const int base = ((((r0 >> 4) + u) * 4 + nt) << 8) + l16;
                #pragma unroll
                for (int r = 0; r < 4; ++r)
                    qbf[base + (quad * 4 + r) * 16] =
                        __float2bfloat16((acc[t][u][r] + bl) * QSCALE);
            }
        } else if (mat == 1) {
            const int kq = (r0 >> 5) * 2048 + (nt >> 1) * 512 +
                           ((nt & 1) * 2 + (l16 >> 3)) * 128 + quad * 32 + (l16 & 7);
            #pragma unroll
            for (int u = 0; u < 2; ++u)
                #pragma unroll
                for (int r = 0; r < 4; ++r)
                    kbf[kq + u * 1024 + r * 8] = __float2bfloat16(acc[t][u][r] + bl);
        } else {
            #pragma unroll
            for (int u = 0; u < 2; ++u)
                #pragma unroll
                for (int r = 0; r < 4; ++r)
                    vbuf[(u * 16 + quad * 4 + r) * 66 + nt * 16 + l16] = acc[t][u][r] + bl;
        }
    }
    __syncthreads();

    // ---- V normalize phase (block-wide) ----
    const int rl = tid >> 3;
    const int jj = tid & 7;
    float ss = 0.f;
    #pragma unroll
    for (int i = 0; i < 8; ++i) {
        float x = vbuf[rl * 66 + jj * 8 + i];
        ss += x * x;
    }
    ss += __shfl_xor(ss, 1, 64);
    ss += __shfl_xor(ss, 2, 64);
    ss += __shfl_xor(ss, 4, 64);
    if (jj == 0) invb[rl] = rsqrtf(fmaxf(ss, 1e-24f));
    __syncthreads();
    float inv = invb[rl];
    bf16x8 vpk;
    #pragma unroll
    for (int i = 0; i < 8; ++i)
        vpk[i] = (__bf16)(vbuf[rl * 66 + jj * 8 + i] * inv);
    *(bf16x8*)(vnb + (size_t)(r0 + rl) * 64 + jj * 8) = vpk;

    const int tl = tid & 15;
    const int n  = (tid >> 4) & 3;
    const int s_ = tid >> 6;
    bf16x8 pack;
    #pragma unroll
    for (int j = 0; j < 8; ++j) {
        int key = s_ * 8 + j;
        pack[j] = (__bf16)(vbuf[key * 66 + n * 16 + tl] * invb[key]);
    }
    const int e1 = (r0 >> 5) * 2048 + (s_ >> 1) * 1024 + (n >> 1) * 512 +
                   (s_ & 1) * 256 + tl * 8 + (n & 1) * 4;
    bf16x4 plo = __builtin_shufflevector(pack, pack, 0, 1, 2, 3);
    bf16x4 phi = __builtin_shufflevector(pack, pack, 4, 5, 6, 7);
    *(bf16x4*)(vbf + e1)       = plo;
    *(bf16x4*)(vbf + e1 + 128) = phi;
}

// ---------------------------------------------------------------------------
// Kernel 2: attention. grid = 512 = qb(32) x bg(16); block = 256 q-rows x
// 512 keys; 2 blocks/CU. K/V LDS-staged, double buffered.
//
// ROUND 13: Opart/lpart partial stores are NON-TEMPORAL. Theory: the 32 MB
// partial-store stream flows through each XCD's 4 MB L2, continuously
// evicting the 2 MB K/V reuse set -> K/V loads miss to L3/HBM (~600-900cy),
// exceeding the 1-chunk prefetch distance -> the measured ~80%-idle attn
// (MfmaUtil 17 / VALUBusy 19 / Occ 31 at ~2000 cyc/iter). nt stores don't
// allocate L2 lines, protecting K/V residency. finish reads Opart nt too
// (single-use stream). Arithmetic bit-identical to r12.
#define STAGE_W(BUF, KR, VR) do {                                            \
        *(float4*)((BUF) + stb) = KR;                                        \
        *(float4*)((BUF) + 4096 + stb) = VR; } while (0)
#define STAGE_L(KR, VR) do {                                                 \
        KR = *(const float4*)gk; VR = *(const float4*)gv;                    \
        gk += 4096; gv += 4096; } while (0)

#define COMPUTE(BUF) do {                                                    \
    const char* kbp = (BUF);                                                 \
    const char* vbp = (BUF) + 4096;                                          \
    bf16x8 k00 = *(const bf16x8*)(kbp + lb);                                 \
    bf16x8 k01 = *(const bf16x8*)(kbp + lb + 1024);                          \
    bf16x8 k10 = *(const bf16x8*)(kbp + lb + 2048);                          \
    bf16x8 k11 = *(const bf16x8*)(kbp + lb + 3072);                          \
    s16x8 W0 = *(const s16x8*)(vbp + lb);                                    \
    s16x8 W1 = *(const s16x8*)(vbp + lb + 1024);                             \
    s16x8 W2 = *(const s16x8*)(vbp + lb + 2048);                             \
    s16x8 W3 = *(const s16x8*)(vbp + lb + 3072);                             \
    const f32x4 zero = (f32x4){0.f, 0.f, 0.f, 0.f};                          \
    _Pragma("unroll")                                                        \
    for (int u = 0; u < 4; ++u) {                                            \
        f32x4 s0 = mfma16(k00, qf32[u][0], zero);                            \
        s0       = mfma16(k01, qf32[u][1], s0);                              \
        f32x4 s1 = mfma16(k10, qf32[u][0], zero);                            \
        s1       = mfma16(k11, qf32[u][1], s1);                              \
        union { bf16x4 v; s16x4 s; } pf0, pf1;                               \
        _Pragma("unroll")                                                    \
        for (int r = 0; r < 4; ++r) {                                        \
            float p0 = __builtin_amdgcn_exp2f(s0[r]);                        \
            float p1 = __builtin_amdgcn_exp2f(s1[r]);                        \
            lp[u] += p0 + p1;                                                \
            pf0.v[r] = (__bf16)p0;                                           \
            pf1.v[r] = (__bf16)p1;                                           \
        }                                                                    \
        of[u][0] = mfma1k(pf0.s, vlo(W0), of[u][0]);                         \
        of[u][0] = mfma1k(pf1.s, vlo(W2), of[u][0]);                         \
        of[u][1] = mfma1k(pf0.s, vhi(W0), of[u][1]);                         \
        of[u][1] = mfma1k(pf1.s, vhi(W2), of[u][1]);                         \
        of[u][2] = mfma1k(pf0.s, vlo(W1), of[u][2]);                         \
        of[u][2] = mfma1k(pf1.s, vlo(W3), of[u][2]);                         \
        of[u][3] = mfma1k(pf0.s, vhi(W1), of[u][3]);                         \
        of[u][3] = mfma1k(pf1.s, vhi(W3), of[u][3]);                         \
    } } while (0)

__global__ __launch_bounds__(256, 2) void attn_kernel(
    const __hip_bfloat16* __restrict__ qbf,
    const __hip_bfloat16* __restrict__ kbf,
    const __hip_bfloat16* __restrict__ vbf,
    float* __restrict__ Opart, float* __restrict__ lpart,
    float* __restrict__ outz)
{
    __shared__ __align__(16) char pool[16384];
    char* bufA = pool;
    char* bufB = pool + 8192;

    const int tid = threadIdx.x;
    if (blockIdx.x == 0) {
        #pragma unroll
        for (int z = 0; z < 4; ++z)
            ((float4*)outz)[tid * 4 + z] = (float4){0.f, 0.f, 0.f, 0.f};
    }

    const int w    = tid >> 6;
    const int lane = tid & 63;
    const int l16  = lane & 15;
    const int quad = lane >> 4;
    const int qb   = blockIdx.x >> 4;
    const int bg   = blockIdx.x & 15;
    const int r0   = qb * 256 + w * 64;               // 64 q-rows per wave
    const int fo32 = l16 * 16 + (quad & 1) * 8;
    const int qh   = quad >> 1;
    const int lb   = lane * 16;
    const int stb  = tid * 16;

    bf16x8 qf32[4][2];
    #pragma unroll
    for (int u = 0; u < 4; ++u)
        #pragma unroll
        for (int p = 0; p < 2; ++p)
            qf32[u][p] = *(const bf16x8*)(qbf +
                ((((r0 >> 4) + u) * 4 + p * 2 + qh) << 8) + fo32);

    f32x4 of[4][4];
    float lp[4] = {0.f, 0.f, 0.f, 0.f};
    #pragma unroll
    for (int u = 0; u < 4; ++u)
        #pragma unroll
        for (int n = 0; n < 4; ++n)
            of[u][n] = (f32x4){0.f, 0.f, 0.f, 0.f};

    const char* gk = (const char*)kbf + (size_t)(bg * 16) * 4096 + stb;
    const char* gv = (const char*)vbf + (size_t)(bg * 16) * 4096 + stb;

    float4 ka, va, kb_, vb_;
    STAGE_L(ka, va);
    STAGE_W(bufA, ka, va);
    STAGE_L(kb_, vb_);
    __syncthreads();

    #pragma unroll 1
    for (int body = 0; body < 7; ++body) {
        STAGE_W(bufB, kb_, vb_);
        STAGE_L(ka, va);
        COMPUTE(bufA);
        __syncthreads();
        STAGE_W(bufA, ka, va);
        STAGE_L(kb_, vb_);
        COMPUTE(bufB);
        __syncthreads();
    }
    STAGE_W(bufB, kb_, vb_);
    COMPUTE(bufA);
    __syncthreads();
    COMPUTE(bufB);

    #pragma unroll
    for (int u = 0; u < 4; ++u) {
        float v = lp[u];
        v += __shfl_xor(v, 16, 64);
        v += __shfl_xor(v, 32, 64);
        lp[u] = v;
    }

    // row-major-partials store: Opart[row][bg][64], lpart[row][bg]
    // NON-TEMPORAL: never re-read by this kernel; keep out of L2 so the
    // K/V reuse set stays resident.
    #pragma unroll
    for (int u = 0; u < 4; ++u)
        #pragma unroll
        for (int n = 0; n < 4; ++n)
            #pragma unroll
            for (int r = 0; r < 4; ++r)
                __builtin_nontemporal_store(of[u][n][r],
                    &Opart[((size_t)(r0 + u * 16 + quad * 4 + r) * 16 + bg) * 64
                           + n * 16 + l16]);
    if (quad == 0) {
        #pragma unroll
        for (int u = 0; u < 4; ++u)
            __builtin_nontemporal_store(lp[u],
                &lpart[(r0 + u * 16 + l16) * 16 + bg]);
    }
}

// ---------------------------------------------------------------------------
// Kernel 3: FUSED combine + sim. grid = 128 blocks x 512 thr; block a owns
// contraction k-range [a*64, a*64+64), needing exactly rows {(b,a) : b<64}.
// Phase 1: sum 16 partials/row (contiguous 4KB stream, NON-TEMPORAL reads),
// /lsum, l2-normalize, bf16 -> LDS. Phase 2: 8 waves = mi(4) x ks(2) GEMM,
// atomicAdd into out (zeroed by attn block 0).
__global__ __launch_bounds__(512) void finish_kernel(
    const float* __restrict__ Opart, const float* __restrict__ lpart,
    const __hip_bfloat16* __restrict__ vnb,
    float* __restrict__ out)
{
    __shared__ __hip_bfloat16 qn[64][68];

    const int a   = blockIdx.x;                       // 0..127
    const int tid = threadIdx.x;                      // 0..511

    // ---- phase 1: 8 threads per row (8 cols each) ----
    {
        const int b  = tid >> 3;                      // 0..63
        const int c8 = tid & 7;
        const int r  = b * 128 + a;
        float acc[8] = {0.f, 0.f, 0.f, 0.f, 0.f, 0.f, 0.f, 0.f};
        #pragma unroll
        for (int g = 0; g < 16; ++g) {
            const f32x4* src = (const f32x4*)(Opart +
                ((size_t)r * 16 + g) * 64 + c8 * 8);
            f32x4 t0 = __builtin_nontemporal_load(src);
            f32x4 t1 = __builtin_nontemporal_load(src + 1);
            acc[0] += t0[0]; acc[1] += t0[1]; acc[2] += t0[2]; acc[3] += t0[3];
            acc[4] += t1[0]; acc[5] += t1[1]; acc[6] += t1[2]; acc[7] += t1[3];
        }
        float lsum = __builtin_nontemporal_load(&lpart[r * 16 + c8 * 2]) +
                     __builtin_nontemporal_load(&lpart[r * 16 + c8 * 2 + 1]);
        lsum += __shfl_xor(lsum, 1, 64);
        lsum += __shfl_xor(lsum, 2, 64);
        lsum += __shfl_xor(lsum, 4, 64);
        const float inv_l = 1.0f / lsum;
        float ss = 0.f;
        #pragma unroll
        for (int c = 0; c < 8; ++c) {
            acc[c] *= inv_l;
            ss += acc[c] * acc[c];
        }
        ss += __shfl_xor(ss, 1, 64);
        ss += __shfl_xor(ss, 2, 64);
        ss += __shfl_xor(ss, 4, 64);
        const float inv = rsqrtf(fmaxf(ss, 1e-24f));
        bf16x8 pk;
        #pragma unroll
        for (int c = 0; c < 8; ++c)
            pk[c] = (__bf16)(acc[c] * inv);
        *(bf16x8*)&qn[b][c8 * 8] = pk;
    }
    __syncthreads();

    // ---- phase 2: GEMM, 8 waves = mi(4) x ks(2) ----
    {
        const int w    = tid >> 6;
        const int lane = tid & 63;
        const int l16  = lane & 15;
        const int quad = lane >> 4;
        const int ks   = w & 1;
        const int mi   = w >> 1;
        const int dq   = ks * 32 + quad * 8;

        bf16x8 af = *(const bf16x8*)(vnb +
            (size_t)(mi * 16 + l16) * 8192 + a * 64 + dq);
        f32x4 accd[4];
        #pragma unroll
        for (int ni = 0; ni < 4; ++ni) {
            bf16x8 bfv = *(const bf16x8*)&qn[ni * 16 + l16][dq];
            accd[ni] = mfma16(af, bfv, (f32x4){0.f, 0.f, 0.f, 0.f});
        }
        #pragma unroll
        for (int ni = 0; ni < 4; ++ni)
            #pragma unroll
            for (int r = 0; r < 4; ++r)
                atomicAdd(&out[(mi * 16 + quad * 4 + r) * 64 + ni * 16 + l16],
                          accd[ni][r] * (1.f / 128.f));
    }
}

// ---------------------------------------------------------------------------
extern "C" void kernel_launch(void* const* d_in, const int* in_sizes, int n_in,
                              void* d_out, int out_size, void* d_ws, size_t ws_size,
                              hipStream_t stream)
{
    const float* feat = (const float*)d_in[0];
    const float* Wq   = (const float*)d_in[1];
    const float* bq   = (const float*)d_in[2];
    const float* Wk   = (const float*)d_in[3];
    const float* bk   = (const float*)d_in[4];
    const float* Wv   = (const float*)d_in[5];
    const float* bv   = (const float*)d_in[6];
    float* out = (float*)d_out;

    const size_t MB = 1u << 20;
    char* ws = (char*)d_ws;
    __hip_bfloat16* qbf = (__hip_bfloat16*)(ws);              // 1 MB (frag-tiled, pre-scaled)
    __hip_bfloat16* kbf = (__hip_bfloat16*)(ws + 1 * MB);     // 1 MB (fragment-linear)
    __hip_bfloat16* vbf = (__hip_bfloat16*)(ws + 2 * MB);     // 1 MB (fragment-linear)
    __hip_bfloat16* vnb = (__hip_bfloat16*)(ws + 3 * MB);     // 1 MB (row-major)
    float* Opart = (float*)(ws + 4 * MB);                     // 32 MB (8192 x 16 x 64)
    float* lpart = (float*)(ws + 36 * MB);                    // 512 KB (8192 x 16)

    proj_kernel<<<256, 256, 0, stream>>>(feat, Wq, bq, Wk, bk, Wv, bv,
                                         qbf, kbf, vbf, vnb);
    attn_kernel<<<512, 256, 0, stream>>>(qbf, kbf, vbf, Opart, lpart, out);
    finish_kernel<<<128, 512, 0, stream>>>(Opart, lpart, vnb, out);
}

// Round 14
// 113.195 us; speedup vs baseline: 1.0817x; 1.0817x over previous
//
#include <hip/hip_runtime.h>
#include <hip/hip_bf16.h>

#define NROW 8192   // B*A = 64*128
#define INC  128
#define OUTC 64
#define BG   16     // key-split factor

// Q is pre-scaled by log2(e)/sqrt(64) at projection time, so attention
// computes p = exp2(q'.k) with a single v_exp_f32 per score.
#define QSCALE 0.18033688011112042f

typedef __bf16 bf16x8 __attribute__((ext_vector_type(8)));
typedef __bf16 bf16x4 __attribute__((ext_vector_type(4)));
typedef short  s16x4  __attribute__((ext_vector_type(4)));
typedef short  s16x8  __attribute__((ext_vector_type(8)));
typedef float  f32x4  __attribute__((ext_vector_type(4)));

static __device__ __forceinline__ f32x4 mfma16(bf16x8 a, bf16x8 b, f32x4 c) {
    return __builtin_amdgcn_mfma_f32_16x16x32_bf16(a, b, c, 0, 0, 0);
}
// 16x16x16 bf16 (K=16). C/D of S^T IS the A-operand layout of P for PV.
static __device__ __forceinline__ f32x4 mfma1k(s16x4 a, s16x4 b, f32x4 c) {
    return __builtin_amdgcn_mfma_f32_16x16x16bf16_1k(a, b, c, 0, 0, 0);
}

static __device__ __forceinline__ bf16x8 cvt8(float4 lo, float4 hi) {
    bf16x8 r;
    r[0] = (__bf16)lo.x; r[1] = (__bf16)lo.y; r[2] = (__bf16)lo.z; r[3] = (__bf16)lo.w;
    r[4] = (__bf16)hi.x; r[5] = (__bf16)hi.y; r[6] = (__bf16)hi.z; r[7] = (__bf16)hi.w;
    return r;
}
static __device__ __forceinline__ s16x4 vlo(s16x8 x) {
    return __builtin_shufflevector(x, x, 0, 1, 2, 3);
}
static __device__ __forceinline__ s16x4 vhi(s16x8 x) {
    return __builtin_shufflevector(x, x, 4, 5, 6, 7);
}

// ---------------------------------------------------------------------------
// Kernel 1: projection via MFMA. grid = 256 = b(64) x aq(4), 1 block/CU.
// Slab staged once; 12 n-tiles (3 mats x 4) spread 3-per-wave. qbf is
// frag-tiled + pre-scaled; kbf/vbf fragment-linear (attn LDS staging is a
// linear tid*16 copy, ds_read_b128 conflict-free); vnb row-major normalized.
__global__ __launch_bounds__(256) void proj_kernel(
    const float* __restrict__ feat,
    const float* __restrict__ Wq, const float* __restrict__ bq,
    const float* __restrict__ Wk, const float* __restrict__ bk,
    const float* __restrict__ Wv, const float* __restrict__ bv,
    __hip_bfloat16* __restrict__ qbf, __hip_bfloat16* __restrict__ kbf,
    __hip_bfloat16* __restrict__ vbf, __hip_bfloat16* __restrict__ vnb)
{
    __shared__ float slab[32 * 132];
    __shared__ float vbuf[32 * 66];
    __shared__ float invb[32];

    const int tid = threadIdx.x;
    const int w    = tid >> 6;
    const int lane = tid & 63;
    const int l16  = lane & 15;
    const int quad = lane >> 4;

    const int b   = blockIdx.x >> 2;
    const int a0  = (blockIdx.x & 3) * 32;
    const int r0  = b * 128 + a0;
    const float* fb = feat + (size_t)b * INC * 128;

    for (int i = tid; i < 32 * 128; i += 256) {
        int c = i >> 5, a = i & 31;
        slab[a * 132 + c] = fb[c * 128 + a0 + a];
    }
    __syncthreads();

    f32x4 acc[3][2];
    #pragma unroll
    for (int t = 0; t < 3; ++t)
        #pragma unroll
        for (int u = 0; u < 2; ++u)
            acc[t][u] = (f32x4){0.f, 0.f, 0.f, 0.f};

    #pragma unroll
    for (int kc = 0; kc < 4; ++kc) {
        const int k0 = kc * 32 + quad * 8;
        bf16x8 afr[2];
        #pragma unroll
        for (int u = 0; u < 2; ++u) {
            const float* ar = slab + (u * 16 + l16) * 132 + k0;
            afr[u] = cvt8(*(const float4*)ar, *(const float4*)(ar + 4));
        }
        #pragma unroll
        for (int t = 0; t < 3; ++t) {
            const int tile = w * 3 + t;
            const int mat  = tile >> 2;
            const float* W = (mat == 0) ? Wq : (mat == 1) ? Wk : Wv;
            const float* wr = W + ((tile & 3) * 16 + l16) * INC + k0;
            bf16x8 bfr = cvt8(*(const float4*)wr, *(const float4*)(wr + 4));
            #pragma unroll
            for (int u = 0; u < 2; ++u)
                acc[t][u] = mfma16(afr[u], bfr, acc[t][u]);
        }
    }

    #pragma unroll
    for (int t = 0; t < 3; ++t) {
        const int tile = w * 3 + t;
        const int mat  = tile >> 2;
        const int nt   = tile & 3;
        const float* bias = (mat == 0) ? bq : (mat == 1) ? bk : bv;
        const float bl = bias[nt * 16 + l16];
        if (mat == 0) {
            #pragma unroll
            for (int u = 0; u < 2; ++u) {
                const int base = ((((r0 >> 4) + u) * 4 + nt) << 8) + l16;
                #pragma unroll
                for (int r = 0; r < 4; ++r)
                    qbf[base + (quad * 4 + r) * 16] =
                        __float2bfloat16((acc[t][u][r] + bl) * QSCALE);
            }
        } else if (mat == 1) {
            const int kq = (r0 >> 5) * 2048 + (nt >> 1) * 512 +
                           ((nt & 1) * 2 + (l16 >> 3)) * 128 + quad * 32 + (l16 & 7);
            #pragma unroll
            for (int u = 0; u < 2; ++u)
                #pragma unroll
                for (int r = 0; r < 4; ++r)
                    kbf[kq + u * 1024 + r * 8] = __float2bfloat16(acc[t][u][r] + bl);
        } else {
            #pragma unroll
            for (int u = 0; u < 2; ++u)
                #pragma unroll
                for (int r = 0; r < 4; ++r)
                    vbuf[(u * 16 + quad * 4 + r) * 66 + nt * 16 + l16] = acc[t][u][r] + bl;
        }
    }
    __syncthreads();

    // ---- V normalize phase (block-wide) ----
    const int rl = tid >> 3;
    const int jj = tid & 7;
    float ss = 0.f;
    #pragma unroll
    for (int i = 0; i < 8; ++i) {
        float x = vbuf[rl * 66 + jj * 8 + i];
        ss += x * x;
    }
    ss += __shfl_xor(ss, 1, 64);
    ss += __shfl_xor(ss, 2, 64);
    ss += __shfl_xor(ss, 4, 64);
    if (jj == 0) invb[rl] = rsqrtf(fmaxf(ss, 1e-24f));
    __syncthreads();
    float inv = invb[rl];
    bf16x8 vpk;
    #pragma unroll
    for (int i = 0; i < 8; ++i)
        vpk[i] = (__bf16)(vbuf[rl * 66 + jj * 8 + i] * inv);
    *(bf16x8*)(vnb + (size_t)(r0 + rl) * 64 + jj * 8) = vpk;

    const int tl = tid & 15;
    const int n  = (tid >> 4) & 3;
    const int s_ = tid >> 6;
    bf16x8 pack;
    #pragma unroll
    for (int j = 0; j < 8; ++j) {
        int key = s_ * 8 + j;
        pack[j] = (__bf16)(vbuf[key * 66 + n * 16 + tl] * invb[key]);
    }
    const int e1 = (r0 >> 5) * 2048 + (s_ >> 1) * 1024 + (n >> 1) * 512 +
                   (s_ & 1) * 256 + tl * 8 + (n & 1) * 4;
    bf16x4 plo = __builtin_shufflevector(pack, pack, 0, 1, 2, 3);
    bf16x4 phi = __builtin_shufflevector(pack, pack, 4, 5, 6, 7);
    *(bf16x4*)(vbf + e1)       = plo;
    *(bf16x4*)(vbf + e1 + 128) = phi;
}

// ---------------------------------------------------------------------------
// Kernel 2: attention. grid = 512 = qb(32) x bg(16); block = 256 q-rows x
// 512 keys; 2 blocks/CU. K/V LDS-staged, double buffered.
//
// ROUND 14 (on top of r12; r13's nt stores REVERTED -- they forced the
// 32MB Opart stream to HBM round-trip, -10us): the loop barriers are now
// RAW s_barrier preceded only by `s_waitcnt lgkmcnt(0)`. __syncthreads()
// emits `s_waitcnt vmcnt(0) lgkmcnt(0)` before s_barrier, draining the
// NEXT chunk's prefetch loads at every one of the 16 chunk barriers
// (T4: counted vmcnt, never 0, is the documented fix). Hazard audit:
// RAW on LDS -- each wave drains its own ds_writes (lgkmcnt(0)) before
// arriving; WAR -- ds_reads are consumed by MFMAs before the barrier;
// in-flight global loads target the issuing wave's own registers (no
// cross-wave hazard), and the compiler inserts counted vmcnt waits at
// their use in STAGE_W.
#define STAGE_W(BUF, KR, VR) do {                                            \
        *(float4*)((BUF) + stb) = KR;                                        \
        *(float4*)((BUF) + 4096 + stb) = VR; } while (0)
#define STAGE_L(KR, VR) do {                                                 \
        KR = *(const float4*)gk; VR = *(const float4*)gv;                    \
        gk += 4096; gv += 4096; } while (0)

#define BARRIER_KEEP_VMCNT() do {                                            \
        asm volatile("s_waitcnt lgkmcnt(0)" ::: "memory");                   \
        __builtin_amdgcn_s_barrier(); } while (0)

#define COMPUTE(BUF) do {                                                    \
    const char* kbp = (BUF);                                                 \
    const char* vbp = (BUF) + 4096;                                          \
    bf16x8 k00 = *(const bf16x8*)(kbp + lb);                                 \
    bf16x8 k01 = *(const bf16x8*)(kbp + lb + 1024);                          \
    bf16x8 k10 = *(const bf16x8*)(kbp + lb + 2048);                          \
    bf16x8 k11 = *(const bf16x8*)(kbp + lb + 3072);                          \
    s16x8 W0 = *(const s16x8*)(vbp + lb);                                    \
    s16x8 W1 = *(const s16x8*)(vbp + lb + 1024);                             \
    s16x8 W2 = *(const s16x8*)(vbp + lb + 2048);                             \
    s16x8 W3 = *(const s16x8*)(vbp + lb + 3072);                             \
    const f32x4 zero = (f32x4){0.f, 0.f, 0.f, 0.f};                          \
    _Pragma("unroll")                                                        \
    for (int u = 0; u < 4; ++u) {                                            \
        f32x4 s0 = mfma16(k00, qf32[u][0], zero);                            \
        s0       = mfma16(k01, qf32[u][1], s0);                              \
        f32x4 s1 = mfma16(k10, qf32[u][0], zero);                            \
        s1       = mfma16(k11, qf32[u][1], s1);                              \
        union { bf16x4 v; s16x4 s; } pf0, pf1;                               \
        _Pragma("unroll")                                                    \
        for (int r = 0; r < 4; ++r) {                                        \
            float p0 = __builtin_amdgcn_exp2f(s0[r]);                        \
            float p1 = __builtin_amdgcn_exp2f(s1[r]);                        \
            lp[u] += p0 + p1;                                                \
            pf0.v[r] = (__bf16)p0;                                           \
            pf1.v[r] = (__bf16)p1;                                           \
        }                                                                    \
        of[u][0] = mfma1k(pf0.s, vlo(W0), of[u][0]);                         \
        of[u][0] = mfma1k(pf1.s, vlo(W2), of[u][0]);                         \
        of[u][1] = mfma1k(pf0.s, vhi(W0), of[u][1]);                         \
        of[u][1] = mfma1k(pf1.s, vhi(W2), of[u][1]);                         \
        of[u][2] = mfma1k(pf0.s, vlo(W1), of[u][2]);                         \
        of[u][2] = mfma1k(pf1.s, vlo(W3), of[u][2]);                         \
        of[u][3] = mfma1k(pf0.s, vhi(W1), of[u][3]);                         \
        of[u][3] = mfma1k(pf1.s, vhi(W3), of[u][3]);                         \
    } } while (0)

__global__ __launch_bounds__(256, 2) void attn_kernel(
    const __hip_bfloat16* __restrict__ qbf,
    const __hip_bfloat16* __restrict__ kbf,
    const __hip_bfloat16* __restrict__ vbf,
    float* __restrict__ Opart, float* __restrict__ lpart,
    float* __restrict__ outz)
{
    __shared__ __align__(16) char pool[16384];
    char* bufA = pool;
    char* bufB = pool + 8192;

    const int tid = threadIdx.x;
    if (blockIdx.x == 0) {
        #pragma unroll
        for (int z = 0; z < 4; ++z)
            ((float4*)outz)[tid * 4 + z] = (float4){0.f, 0.f, 0.f, 0.f};
    }

    const int w    = tid >> 6;
    const int lane = tid & 63;
    const int l16  = lane & 15;
    const int quad = lane >> 4;
    const int qb   = blockIdx.x >> 4;
    const int bg   = blockIdx.x & 15;
    const int r0   = qb * 256 + w * 64;               // 64 q-rows per wave
    const int fo32 = l16 * 16 + (quad & 1) * 8;
    const int qh   = quad >> 1;
    const int lb   = lane * 16;
    const int stb  = tid * 16;

    bf16x8 qf32[4][2];
    #pragma unroll
    for (int u = 0; u < 4; ++u)
        #pragma unroll
        for (int p = 0; p < 2; ++p)
            qf32[u][p] = *(const bf16x8*)(qbf +
                ((((r0 >> 4) + u) * 4 + p * 2 + qh) << 8) + fo32);

    f32x4 of[4][4];
    float lp[4] = {0.f, 0.f, 0.f, 0.f};
    #pragma unroll
    for (int u = 0; u < 4; ++u)
        #pragma unroll
        for (int n = 0; n < 4; ++n)
            of[u][n] = (f32x4){0.f, 0.f, 0.f, 0.f};

    const char* gk = (const char*)kbf + (size_t)(bg * 16) * 4096 + stb;
    const char* gv = (const char*)vbf + (size_t)(bg * 16) * 4096 + stb;

    float4 ka, va, kb_, vb_;
    STAGE_L(ka, va);
    STAGE_W(bufA, ka, va);
    STAGE_L(kb_, vb_);
    BARRIER_KEEP_VMCNT();                             // bufA ready

    #pragma unroll 1
    for (int body = 0; body < 7; ++body) {
        STAGE_W(bufB, kb_, vb_);
        STAGE_L(ka, va);
        COMPUTE(bufA);
        BARRIER_KEEP_VMCNT();
        STAGE_W(bufA, ka, va);
        STAGE_L(kb_, vb_);
        COMPUTE(bufB);
        BARRIER_KEEP_VMCNT();
    }
    STAGE_W(bufB, kb_, vb_);
    COMPUTE(bufA);
    BARRIER_KEEP_VMCNT();
    COMPUTE(bufB);

    #pragma unroll
    for (int u = 0; u < 4; ++u) {
        float v = lp[u];
        v += __shfl_xor(v, 16, 64);
        v += __shfl_xor(v, 32, 64);
        lp[u] = v;
    }

    // row-major-partials store: Opart[row][bg][64], lpart[row][bg]
    // (plain cached stores -- r13 proved nt costs a HBM round-trip)
    #pragma unroll
    for (int u = 0; u < 4; ++u)
        #pragma unroll
        for (int n = 0; n < 4; ++n)
            #pragma unroll
            for (int r = 0; r < 4; ++r)
                Opart[((size_t)(r0 + u * 16 + quad * 4 + r) * 16 + bg) * 64
                      + n * 16 + l16] = of[u][n][r];
    if (quad == 0) {
        #pragma unroll
        for (int u = 0; u < 4; ++u)
            lpart[(r0 + u * 16 + l16) * 16 + bg] = lp[u];
    }
}

// ---------------------------------------------------------------------------
// Kernel 3: FUSED combine + sim. grid = 128 blocks x 512 thr; block a owns
// contraction k-range [a*64, a*64+64), needing exactly rows {(b,a) : b<64}.
// Phase 1: sum 16 partials/row (contiguous 4KB stream), /lsum, l2-normalize,
// bf16 -> LDS qn[64][68]. Phase 2: 8 waves = mi(4) x ks(2) GEMM, atomicAdd
// into out (zeroed by attn block 0).
__global__ __launch_bounds__(512) void finish_kernel(
    const float* __restrict__ Opart, const float* __restrict__ lpart,
    const __hip_bfloat16* __restrict__ vnb,
    float* __restrict__ out)
{
    __shared__ __hip_bfloat16 qn[64][68];

    const int a   = blockIdx.x;                       // 0..127
    const int tid = threadIdx.x;                      // 0..511

    // ---- phase 1: 8 threads per row (8 cols each) ----
    {
        const int b  = tid >> 3;                      // 0..63
        const int c8 = tid & 7;
        const int r  = b * 128 + a;
        float acc[8] = {0.f, 0.f, 0.f, 0.f, 0.f, 0.f, 0.f, 0.f};
        #pragma unroll
        for (int g = 0; g < 16; ++g) {
            const float* src = Opart + ((size_t)r * 16 + g) * 64 + c8 * 8;
            float4 t0 = *(const float4*)(src);
            float4 t1 = *(const float4*)(src + 4);
            acc[0] += t0.x; acc[1] += t0.y; acc[2] += t0.z; acc[3] += t0.w;
            acc[4] += t1.x; acc[5] += t1.y; acc[6] += t1.z; acc[7] += t1.w;
        }
        float lsum = lpart[r * 16 + c8 * 2] + lpart[r * 16 + c8 * 2 + 1];
        lsum += __shfl_xor(lsum, 1, 64);
        lsum += __shfl_xor(lsum, 2, 64);
        lsum += __shfl_xor(lsum, 4, 64);
        const float inv_l = 1.0f / lsum;
        float ss = 0.f;
        #pragma unroll
        for (int c = 0; c < 8; ++c) {
            acc[c] *= inv_l;
            ss += acc[c] * acc[c];
        }
        ss += __shfl_xor(ss, 1, 64);
        ss += __shfl_xor(ss, 2, 64);
        ss += __shfl_xor(ss, 4, 64);
        const float inv = rsqrtf(fmaxf(ss, 1e-24f));
        bf16x8 pk;
        #pragma unroll
        for (int c = 0; c < 8; ++c)
            pk[c] = (__bf16)(acc[c] * inv);
        *(bf16x8*)&qn[b][c8 * 8] = pk;
    }
    __syncthreads();

    // ---- phase 2: GEMM, 8 waves = mi(4) x ks(2) ----
    {
        const int w    = tid >> 6;
        const int lane = tid & 63;
        const int l16  = lane & 15;
        const int quad = lane >> 4;
        const int ks   = w & 1;
        const int mi   = w >> 1;
        const int dq   = ks * 32 + quad * 8;

        bf16x8 af = *(const bf16x8*)(vnb +
            (size_t)(mi * 16 + l16) * 8192 + a * 64 + dq);
        f32x4 accd[4];
        #pragma unroll
        for (int ni = 0; ni < 4; ++ni) {
            bf16x8 bfv = *(const bf16x8*)&qn[ni * 16 + l16][dq];
            accd[ni] = mfma16(af, bfv, (f32x4){0.f, 0.f, 0.f, 0.f});
        }
        #pragma unroll
        for (int ni = 0; ni < 4; ++ni)
            #pragma unroll
            for (int r = 0; r < 4; ++r)
                atomicAdd(&out[(mi * 16 + quad * 4 + r) * 64 + ni * 16 + l16],
                          accd[ni][r] * (1.f / 128.f));
    }
}

// ---------------------------------------------------------------------------
extern "C" void kernel_launch(void* const* d_in, const int* in_sizes, int n_in,
                              void* d_out, int out_size, void* d_ws, size_t ws_size,
                              hipStream_t stream)
{
    const float* feat = (const float*)d_in[0];
    const float* Wq   = (const float*)d_in[1];
    const float* bq   = (const float*)d_in[2];
    const float* Wk   = (const float*)d_in[3];
    const float* bk   = (const float*)d_in[4];
    const float* Wv   = (const float*)d_in[5];
    const float* bv   = (const float*)d_in[6];
    float* out = (float*)d_out;

    const size_t MB = 1u << 20;
    char* ws = (char*)d_ws;
    __hip_bfloat16* qbf = (__hip_bfloat16*)(ws);              // 1 MB (frag-tiled, pre-scaled)
    __hip_bfloat16* kbf = (__hip_bfloat16*)(ws + 1 * MB);     // 1 MB (fragment-linear)
    __hip_bfloat16* vbf = (__hip_bfloat16*)(ws + 2 * MB);     // 1 MB (fragment-linear)
    __hip_bfloat16* vnb = (__hip_bfloat16*)(ws + 3 * MB);     // 1 MB (row-major)
    float* Opart = (float*)(ws + 4 * MB);                     // 32 MB (8192 x 16 x 64)
    float* lpart = (float*)(ws + 36 * MB);                    // 512 KB (8192 x 16)

    proj_kernel<<<256, 256, 0, stream>>>(feat, Wq, bq, Wk, bk, Wv, bv,
                                         qbf, kbf, vbf, vnb);
    attn_kernel<<<512, 256, 0, stream>>>(qbf, kbf, vbf, Opart, lpart, out);
    finish_kernel<<<128, 512, 0, stream>>>(Opart, lpart, vnb, out);
}

// Round 15
// 110.350 us; speedup vs baseline: 1.1096x; 1.0258x over previous
//
#include <hip/hip_runtime.h>
#include <hip/hip_bf16.h>

#define NROW 8192   // B*A = 64*128
#define INC  128
#define OUTC 64
#define BG   16     // key-split factor

// Q is pre-scaled by log2(e)/sqrt(64) at projection time, so attention
// computes p = exp2(q'.k) with a single v_exp_f32 per score.
#define QSCALE 0.18033688011112042f

typedef __bf16 bf16x8 __attribute__((ext_vector_type(8)));
typedef __bf16 bf16x4 __attribute__((ext_vector_type(4)));
typedef short  s16x4  __attribute__((ext_vector_type(4)));
typedef short  s16x8  __attribute__((ext_vector_type(8)));
typedef float  f32x4  __attribute__((ext_vector_type(4)));

static __device__ __forceinline__ f32x4 mfma16(bf16x8 a, bf16x8 b, f32x4 c) {
    return __builtin_amdgcn_mfma_f32_16x16x32_bf16(a, b, c, 0, 0, 0);
}
// 16x16x16 bf16 (K=16). C/D of S^T IS the A-operand layout of P for PV.
static __device__ __forceinline__ f32x4 mfma1k(s16x4 a, s16x4 b, f32x4 c) {
    return __builtin_amdgcn_mfma_f32_16x16x16bf16_1k(a, b, c, 0, 0, 0);
}

static __device__ __forceinline__ bf16x8 cvt8(float4 lo, float4 hi) {
    bf16x8 r;
    r[0] = (__bf16)lo.x; r[1] = (__bf16)lo.y; r[2] = (__bf16)lo.z; r[3] = (__bf16)lo.w;
    r[4] = (__bf16)hi.x; r[5] = (__bf16)hi.y; r[6] = (__bf16)hi.z; r[7] = (__bf16)hi.w;
    return r;
}
static __device__ __forceinline__ s16x4 vlo(s16x8 x) {
    return __builtin_shufflevector(x, x, 0, 1, 2, 3);
}
static __device__ __forceinline__ s16x4 vhi(s16x8 x) {
    return __builtin_shufflevector(x, x, 4, 5, 6, 7);
}

// ---------------------------------------------------------------------------
// Kernel 1: projection via MFMA. grid = 256 = b(64) x aq(4), 1 block/CU.
// Slab staged once; 12 n-tiles (3 mats x 4) spread 3-per-wave. qbf is
// frag-tiled + pre-scaled; kbf/vbf fragment-linear (attn LDS staging is a
// linear tid*16 copy, ds_read_b128 conflict-free); vnb row-major normalized.
__global__ __launch_bounds__(256) void proj_kernel(
    const float* __restrict__ feat,
    const float* __restrict__ Wq, const float* __restrict__ bq,
    const float* __restrict__ Wk, const float* __restrict__ bk,
    const float* __restrict__ Wv, const float* __restrict__ bv,
    __hip_bfloat16* __restrict__ qbf, __hip_bfloat16* __restrict__ kbf,
    __hip_bfloat16* __restrict__ vbf, __hip_bfloat16* __restrict__ vnb)
{
    __shared__ float slab[32 * 132];
    __shared__ float vbuf[32 * 66];
    __shared__ float invb[32];

    const int tid = threadIdx.x;
    const int w    = tid >> 6;
    const int lane = tid & 63;
    const int l16  = lane & 15;
    const int quad = lane >> 4;

    const int b   = blockIdx.x >> 2;
    const int a0  = (blockIdx.x & 3) * 32;
    const int r0  = b * 128 + a0;
    const float* fb = feat + (size_t)b * INC * 128;

    for (int i = tid; i < 32 * 128; i += 256) {
        int c = i >> 5, a = i & 31;
        slab[a * 132 + c] = fb[c * 128 + a0 + a];
    }
    __syncthreads();

    f32x4 acc[3][2];
    #pragma unroll
    for (int t = 0; t < 3; ++t)
        #pragma unroll
        for (int u = 0; u < 2; ++u)
            acc[t][u] = (f32x4){0.f, 0.f, 0.f, 0.f};

    #pragma unroll
    for (int kc = 0; kc < 4; ++kc) {
        const int k0 = kc * 32 + quad * 8;
        bf16x8 afr[2];
        #pragma unroll
        for (int u = 0; u < 2; ++u) {
            const float* ar = slab + (u * 16 + l16) * 132 + k0;
            afr[u] = cvt8(*(const float4*)ar, *(const float4*)(ar + 4));
        }
        #pragma unroll
        for (int t = 0; t < 3; ++t) {
            const int tile = w * 3 + t;
            const int mat  = tile >> 2;
            const float* W = (mat == 0) ? Wq : (mat == 1) ? Wk : Wv;
            const float* wr = W + ((tile & 3) * 16 + l16) * INC + k0;
            bf16x8 bfr = cvt8(*(const float4*)wr, *(const float4*)(wr + 4));
            #pragma unroll
            for (int u = 0; u < 2; ++u)
                acc[t][u] = mfma16(afr[u], bfr, acc[t][u]);
        }
    }

    #pragma unroll
    for (int t = 0; t < 3; ++t) {
        const int tile = w * 3 + t;
        const int mat  = tile >> 2;
        const int nt   = tile & 3;
        const float* bias = (mat == 0) ? bq : (mat == 1) ? bk : bv;
        const float bl = bias[nt * 16 + l16];
        if (mat == 0) {
            #pragma unroll
            for (int u = 0; u < 2; ++u) {
                const int base = ((((r0 >> 4) + u) * 4 + nt) << 8) + l16;
                #pragma unroll
                for (int r = 0; r < 4; ++r)
                    qbf[base + (quad * 4 + r) * 16] =
                        __float2bfloat16((acc[t][u][r] + bl) * QSCALE);
            }
        } else if (mat == 1) {
            const int kq = (r0 >> 5) * 2048 + (nt >> 1) * 512 +
                           ((nt & 1) * 2 + (l16 >> 3)) * 128 + quad * 32 + (l16 & 7);
            #pragma unroll
            for (int u = 0; u < 2; ++u)
                #pragma unroll
                for (int r = 0; r < 4; ++r)
                    kbf[kq + u * 1024 + r * 8] = __float2bfloat16(acc[t][u][r] + bl);
        } else {
            #pragma unroll
            for (int u = 0; u < 2; ++u)
                #pragma unroll
                for (int r = 0; r < 4; ++r)
                    vbuf[(u * 16 + quad * 4 + r) * 66 + nt * 16 + l16] = acc[t][u][r] + bl;
        }
    }
    __syncthreads();

    // ---- V normalize phase (block-wide) ----
    const int rl = tid >> 3;
    const int jj = tid & 7;
    float ss = 0.f;
    #pragma unroll
    for (int i = 0; i < 8; ++i) {
        float x = vbuf[rl * 66 + jj * 8 + i];
        ss += x * x;
    }
    ss += __shfl_xor(ss, 1, 64);
    ss += __shfl_xor(ss, 2, 64);
    ss += __shfl_xor(ss, 4, 64);
    if (jj == 0) invb[rl] = rsqrtf(fmaxf(ss, 1e-24f));
    __syncthreads();
    float inv = invb[rl];
    bf16x8 vpk;
    #pragma unroll
    for (int i = 0; i < 8; ++i)
        vpk[i] = (__bf16)(vbuf[rl * 66 + jj * 8 + i] * inv);
    *(bf16x8*)(vnb + (size_t)(r0 + rl) * 64 + jj * 8) = vpk;

    const int tl = tid & 15;
    const int n  = (tid >> 4) & 3;
    const int s_ = tid >> 6;
    bf16x8 pack;
    #pragma unroll
    for (int j = 0; j < 8; ++j) {
        int key = s_ * 8 + j;
        pack[j] = (__bf16)(vbuf[key * 66 + n * 16 + tl] * invb[key]);
    }
    const int e1 = (r0 >> 5) * 2048 + (s_ >> 1) * 1024 + (n >> 1) * 512 +
                   (s_ & 1) * 256 + tl * 8 + (n & 1) * 4;
    bf16x4 plo = __builtin_shufflevector(pack, pack, 0, 1, 2, 3);
    bf16x4 phi = __builtin_shufflevector(pack, pack, 4, 5, 6, 7);
    *(bf16x4*)(vbf + e1)       = plo;
    *(bf16x4*)(vbf + e1 + 128) = phi;
}

// ---------------------------------------------------------------------------
// Kernel 2: attention. grid = 512 = qb(32) x bg(16); block = 256 q-rows x
// 512 keys; 2 blocks/CU. K/V LDS-staged, double buffered, lgkmcnt-only
// barriers (r14).
//
// ROUND 15: the softmax DENOMINATOR IS DEAD CODE -- finish l2-normalizes
// the row, and l2norm(O/l) = O/||O||, so the 1/l cancels exactly. Deleted:
// lp accumulation (512 VALU adds/lane in the hot loop), the quad shuffle
// reduce, and the lpart buffer/stores. O partials are unnormalized; f32
// range is ample (O ~ l*O(1) <~ 1e4).
#define STAGE_W(BUF, KR, VR) do {                                            \
        *(float4*)((BUF) + stb) = KR;                                        \
        *(float4*)((BUF) + 4096 + stb) = VR; } while (0)
#define STAGE_L(KR, VR) do {                                                 \
        KR = *(const float4*)gk; VR = *(const float4*)gv;                    \
        gk += 4096; gv += 4096; } while (0)

#define BARRIER_KEEP_VMCNT() do {                                            \
        asm volatile("s_waitcnt lgkmcnt(0)" ::: "memory");                   \
        __builtin_amdgcn_s_barrier(); } while (0)

#define COMPUTE(BUF) do {                                                    \
    const char* kbp = (BUF);                                                 \
    const char* vbp = (BUF) + 4096;                                          \
    bf16x8 k00 = *(const bf16x8*)(kbp + lb);                                 \
    bf16x8 k01 = *(const bf16x8*)(kbp + lb + 1024);                          \
    bf16x8 k10 = *(const bf16x8*)(kbp + lb + 2048);                          \
    bf16x8 k11 = *(const bf16x8*)(kbp + lb + 3072);                          \
    s16x8 W0 = *(const s16x8*)(vbp + lb);                                    \
    s16x8 W1 = *(const s16x8*)(vbp + lb + 1024);                             \
    s16x8 W2 = *(const s16x8*)(vbp + lb + 2048);                             \
    s16x8 W3 = *(const s16x8*)(vbp + lb + 3072);                             \
    const f32x4 zero = (f32x4){0.f, 0.f, 0.f, 0.f};                          \
    _Pragma("unroll")                                                        \
    for (int u = 0; u < 4; ++u) {                                            \
        f32x4 s0 = mfma16(k00, qf32[u][0], zero);                            \
        s0       = mfma16(k01, qf32[u][1], s0);                              \
        f32x4 s1 = mfma16(k10, qf32[u][0], zero);                            \
        s1       = mfma16(k11, qf32[u][1], s1);                              \
        union { bf16x4 v; s16x4 s; } pf0, pf1;                               \
        _Pragma("unroll")                                                    \
        for (int r = 0; r < 4; ++r) {                                        \
            pf0.v[r] = (__bf16)__builtin_amdgcn_exp2f(s0[r]);                \
            pf1.v[r] = (__bf16)__builtin_amdgcn_exp2f(s1[r]);                \
        }                                                                    \
        of[u][0] = mfma1k(pf0.s, vlo(W0), of[u][0]);                         \
        of[u][0] = mfma1k(pf1.s, vlo(W2), of[u][0]);                         \
        of[u][1] = mfma1k(pf0.s, vhi(W0), of[u][1]);                         \
        of[u][1] = mfma1k(pf1.s, vhi(W2), of[u][1]);                         \
        of[u][2] = mfma1k(pf0.s, vlo(W1), of[u][2]);                         \
        of[u][2] = mfma1k(pf1.s, vlo(W3), of[u][2]);                         \
        of[u][3] = mfma1k(pf0.s, vhi(W1), of[u][3]);                         \
        of[u][3] = mfma1k(pf1.s, vhi(W3), of[u][3]);                         \
    } } while (0)

__global__ __launch_bounds__(256, 2) void attn_kernel(
    const __hip_bfloat16* __restrict__ qbf,
    const __hip_bfloat16* __restrict__ kbf,
    const __hip_bfloat16* __restrict__ vbf,
    float* __restrict__ Opart,
    float* __restrict__ outz)
{
    __shared__ __align__(16) char pool[16384];
    char* bufA = pool;
    char* bufB = pool + 8192;

    const int tid = threadIdx.x;
    if (blockIdx.x == 0) {
        #pragma unroll
        for (int z = 0; z < 4; ++z)
            ((float4*)outz)[tid * 4 + z] = (float4){0.f, 0.f, 0.f, 0.f};
    }

    const int w    = tid >> 6;
    const int lane = tid & 63;
    const int l16  = lane & 15;
    const int quad = lane >> 4;
    const int qb   = blockIdx.x >> 4;
    const int bg   = blockIdx.x & 15;
    const int r0   = qb * 256 + w * 64;               // 64 q-rows per wave
    const int fo32 = l16 * 16 + (quad & 1) * 8;
    const int qh   = quad >> 1;
    const int lb   = lane * 16;
    const int stb  = tid * 16;

    bf16x8 qf32[4][2];
    #pragma unroll
    for (int u = 0; u < 4; ++u)
        #pragma unroll
        for (int p = 0; p < 2; ++p)
            qf32[u][p] = *(const bf16x8*)(qbf +
                ((((r0 >> 4) + u) * 4 + p * 2 + qh) << 8) + fo32);

    f32x4 of[4][4];
    #pragma unroll
    for (int u = 0; u < 4; ++u)
        #pragma unroll
        for (int n = 0; n < 4; ++n)
            of[u][n] = (f32x4){0.f, 0.f, 0.f, 0.f};

    const char* gk = (const char*)kbf + (size_t)(bg * 16) * 4096 + stb;
    const char* gv = (const char*)vbf + (size_t)(bg * 16) * 4096 + stb;

    float4 ka, va, kb_, vb_;
    STAGE_L(ka, va);
    STAGE_W(bufA, ka, va);
    STAGE_L(kb_, vb_);
    BARRIER_KEEP_VMCNT();                             // bufA ready

    #pragma unroll 1
    for (int body = 0; body < 7; ++body) {
        STAGE_W(bufB, kb_, vb_);
        STAGE_L(ka, va);
        COMPUTE(bufA);
        BARRIER_KEEP_VMCNT();
        STAGE_W(bufA, ka, va);
        STAGE_L(kb_, vb_);
        COMPUTE(bufB);
        BARRIER_KEEP_VMCNT();
    }
    STAGE_W(bufB, kb_, vb_);
    COMPUTE(bufA);
    BARRIER_KEEP_VMCNT();
    COMPUTE(bufB);

    // row-major-partials store: Opart[row][bg][64] (unnormalized O partials)
    #pragma unroll
    for (int u = 0; u < 4; ++u)
        #pragma unroll
        for (int n = 0; n < 4; ++n)
            #pragma unroll
            for (int r = 0; r < 4; ++r)
                Opart[((size_t)(r0 + u * 16 + quad * 4 + r) * 16 + bg) * 64
                      + n * 16 + l16] = of[u][n][r];
}

// ---------------------------------------------------------------------------
// Kernel 3: FUSED combine + sim. grid = 256 blocks x 256 thr:
// block = (a, jhalf) with a = bid>>1 (contraction slice k in [a*64,a*64+64))
// and jhalf = bid&1 (which 32 of the 64 batch rows of Qn this block
// normalizes and multiplies). Doubles CU coverage of the 32 MB Opart read
// vs the 128-block version (phase 1 was BW/occupancy-bound on half the
// device). No lsum: l2norm cancels the softmax denominator. Phase 2 folds
// the K=64 contraction in-register before the atomicAdd (halved atomics).
__global__ __launch_bounds__(256) void finish_kernel(
    const float* __restrict__ Opart,
    const __hip_bfloat16* __restrict__ vnb,
    float* __restrict__ out)
{
    __shared__ __hip_bfloat16 qn[32][68];

    const int a     = blockIdx.x >> 1;                // 0..127
    const int jhalf = blockIdx.x & 1;
    const int tid   = threadIdx.x;                    // 0..255

    // ---- phase 1: 8 threads per row (8 cols each), 32 rows ----
    {
        const int bl = tid >> 3;                      // 0..31 local row
        const int c8 = tid & 7;
        const int r  = (jhalf * 32 + bl) * 128 + a;
        float acc[8] = {0.f, 0.f, 0.f, 0.f, 0.f, 0.f, 0.f, 0.f};
        #pragma unroll
        for (int g = 0; g < 16; ++g) {
            const float* src = Opart + ((size_t)r * 16 + g) * 64 + c8 * 8;
            float4 t0 = *(const float4*)(src);
            float4 t1 = *(const float4*)(src + 4);
            acc[0] += t0.x; acc[1] += t0.y; acc[2] += t0.z; acc[3] += t0.w;
            acc[4] += t1.x; acc[5] += t1.y; acc[6] += t1.z; acc[7] += t1.w;
        }
        // no lsum: l2norm(O/l) == l2norm(O)
        float ss = 0.f;
        #pragma unroll
        for (int c = 0; c < 8; ++c)
            ss += acc[c] * acc[c];
        ss += __shfl_xor(ss, 1, 64);
        ss += __shfl_xor(ss, 2, 64);
        ss += __shfl_xor(ss, 4, 64);
        const float inv = rsqrtf(fmaxf(ss, 1e-24f));
        bf16x8 pk;
        #pragma unroll
        for (int c = 0; c < 8; ++c)
            pk[c] = (__bf16)(acc[c] * inv);
        *(bf16x8*)&qn[bl][c8 * 8] = pk;
    }
    __syncthreads();

    // ---- phase 2: GEMM, 4 waves = mi(4); K=64 folded in-register ----
    {
        const int w    = tid >> 6;                    // mi = 0..3
        const int lane = tid & 63;
        const int l16  = lane & 15;
        const int quad = lane >> 4;

        f32x4 accd[2];
        accd[0] = (f32x4){0.f, 0.f, 0.f, 0.f};
        accd[1] = (f32x4){0.f, 0.f, 0.f, 0.f};
        #pragma unroll
        for (int ks = 0; ks < 2; ++ks) {
            const int dq = ks * 32 + quad * 8;
            bf16x8 af = *(const bf16x8*)(vnb +
                (size_t)(w * 16 + l16) * 8192 + a * 64 + dq);
            #pragma unroll
            for (int ni = 0; ni < 2; ++ni) {
                bf16x8 bfv = *(const bf16x8*)&qn[ni * 16 + l16][dq];
                accd[ni] = mfma16(af, bfv, accd[ni]);
            }
        }
        #pragma unroll
        for (int ni = 0; ni < 2; ++ni)
            #pragma unroll
            for (int r = 0; r < 4; ++r)
                atomicAdd(&out[(w * 16 + quad * 4 + r) * 64 +
                               jhalf * 32 + ni * 16 + l16],
                          accd[ni][r] * (1.f / 128.f));
    }
}

// ---------------------------------------------------------------------------
extern "C" void kernel_launch(void* const* d_in, const int* in_sizes, int n_in,
                              void* d_out, int out_size, void* d_ws, size_t ws_size,
                              hipStream_t stream)
{
    const float* feat = (const float*)d_in[0];
    const float* Wq   = (const float*)d_in[1];
    const float* bq   = (const float*)d_in[2];
    const float* Wk   = (const float*)d_in[3];
    const float* bk   = (const float*)d_in[4];
    const float* Wv   = (const float*)d_in[5];
    const float* bv   = (const float*)d_in[6];
    float* out = (float*)d_out;

    const size_t MB = 1u << 20;
    char* ws = (char*)d_ws;
    __hip_bfloat16* qbf = (__hip_bfloat16*)(ws);              // 1 MB (frag-tiled, pre-scaled)
    __hip_bfloat16* kbf = (__hip_bfloat16*)(ws + 1 * MB);     // 1 MB (fragment-linear)
    __hip_bfloat16* vbf = (__hip_bfloat16*)(ws + 2 * MB);     // 1 MB (fragment-linear)
    __hip_bfloat16* vnb = (__hip_bfloat16*)(ws + 3 * MB);     // 1 MB (row-major)
    float* Opart = (float*)(ws + 4 * MB);                     // 32 MB (8192 x 16 x 64)

    proj_kernel<<<256, 256, 0, stream>>>(feat, Wq, bq, Wk, bk, Wv, bv,
                                         qbf, kbf, vbf, vnb);
    attn_kernel<<<512, 256, 0, stream>>>(qbf, kbf, vbf, Opart, out);
    finish_kernel<<<256, 256, 0, stream>>>(Opart, vnb, out);
}

// Round 16
// 105.737 us; speedup vs baseline: 1.1580x; 1.0436x over previous
//
#include <hip/hip_runtime.h>
#include <hip/hip_bf16.h>

#define NROW 8192   // B*A = 64*128
#define INC  128
#define OUTC 64
#define BG   16     // key-split factor

// Q is pre-scaled by log2(e)/sqrt(64) at projection time, so attention
// computes p = exp2(q'.k) with a single v_exp_f32 per score.
#define QSCALE 0.18033688011112042f

typedef __bf16 bf16x8 __attribute__((ext_vector_type(8)));
typedef __bf16 bf16x4 __attribute__((ext_vector_type(4)));
typedef short  s16x4  __attribute__((ext_vector_type(4)));
typedef short  s16x8  __attribute__((ext_vector_type(8)));
typedef float  f32x4  __attribute__((ext_vector_type(4)));

static __device__ __forceinline__ f32x4 mfma16(bf16x8 a, bf16x8 b, f32x4 c) {
    return __builtin_amdgcn_mfma_f32_16x16x32_bf16(a, b, c, 0, 0, 0);
}
// 16x16x16 bf16 (K=16). C/D of S^T IS the A-operand layout of P for PV.
static __device__ __forceinline__ f32x4 mfma1k(s16x4 a, s16x4 b, f32x4 c) {
    return __builtin_amdgcn_mfma_f32_16x16x16bf16_1k(a, b, c, 0, 0, 0);
}

static __device__ __forceinline__ bf16x8 cvt8(float4 lo, float4 hi) {
    bf16x8 r;
    r[0] = (__bf16)lo.x; r[1] = (__bf16)lo.y; r[2] = (__bf16)lo.z; r[3] = (__bf16)lo.w;
    r[4] = (__bf16)hi.x; r[5] = (__bf16)hi.y; r[6] = (__bf16)hi.z; r[7] = (__bf16)hi.w;
    return r;
}
static __device__ __forceinline__ s16x4 vlo(s16x8 x) {
    return __builtin_shufflevector(x, x, 0, 1, 2, 3);
}
static __device__ __forceinline__ s16x4 vhi(s16x8 x) {
    return __builtin_shufflevector(x, x, 4, 5, 6, 7);
}

// ---------------------------------------------------------------------------
// Kernel 1: projection via MFMA. grid = 256 = b(64) x aq(4), 1 block/CU.
// Slab staged once; 12 n-tiles (3 mats x 4) spread 3-per-wave. qbf is
// frag-tiled + pre-scaled; kbf/vbf fragment-linear (attn LDS staging is a
// linear tid*16 copy, ds_read_b128 conflict-free); vnb row-major normalized.
__global__ __launch_bounds__(256) void proj_kernel(
    const float* __restrict__ feat,
    const float* __restrict__ Wq, const float* __restrict__ bq,
    const float* __restrict__ Wk, const float* __restrict__ bk,
    const float* __restrict__ Wv, const float* __restrict__ bv,
    __hip_bfloat16* __restrict__ qbf, __hip_bfloat16* __restrict__ kbf,
    __hip_bfloat16* __restrict__ vbf, __hip_bfloat16* __restrict__ vnb)
{
    __shared__ float slab[32 * 132];
    __shared__ float vbuf[32 * 66];
    __shared__ float invb[32];

    const int tid = threadIdx.x;
    const int w    = tid >> 6;
    const int lane = tid & 63;
    const int l16  = lane & 15;
    const int quad = lane >> 4;

    const int b   = blockIdx.x >> 2;
    const int a0  = (blockIdx.x & 3) * 32;
    const int r0  = b * 128 + a0;
    const float* fb = feat + (size_t)b * INC * 128;

    for (int i = tid; i < 32 * 128; i += 256) {
        int c = i >> 5, a = i & 31;
        slab[a * 132 + c] = fb[c * 128 + a0 + a];
    }
    __syncthreads();

    f32x4 acc[3][2];
    #pragma unroll
    for (int t = 0; t < 3; ++t)
        #pragma unroll
        for (int u = 0; u < 2; ++u)
            acc[t][u] = (f32x4){0.f, 0.f, 0.f, 0.f};

    #pragma unroll
    for (int kc = 0; kc < 4; ++kc) {
        const int k0 = kc * 32 + quad * 8;
        bf16x8 afr[2];
        #pragma unroll
        for (int u = 0; u < 2; ++u) {
            const float* ar = slab + (u * 16 + l16) * 132 + k0;
            afr[u] = cvt8(*(const float4*)ar, *(const float4*)(ar + 4));
        }
        #pragma unroll
        for (int t = 0; t < 3; ++t) {
            const int tile = w * 3 + t;
            const int mat  = tile >> 2;
            const float* W = (mat == 0) ? Wq : (mat == 1) ? Wk : Wv;
            const float* wr = W + ((tile & 3) * 16 + l16) * INC + k0;
            bf16x8 bfr = cvt8(*(const float4*)wr, *(const float4*)(wr + 4));
            #pragma unroll
            for (int u = 0; u < 2; ++u)
                acc[t][u] = mfma16(afr[u], bfr, acc[t][u]);
        }
    }

    #pragma unroll
    for (int t = 0; t < 3; ++t) {
        const int tile = w * 3 + t;
        const int mat  = tile >> 2;
        const int nt   = tile & 3;
        const float* bias = (mat == 0) ? bq : (mat == 1) ? bk : bv;
        const float bl = bias[nt * 16 + l16];
        if (mat == 0) {
            #pragma unroll
            for (int u = 0; u < 2; ++u) {
                const int base = ((((r0 >> 4) + u) * 4 + nt) << 8) + l16;
                #pragma unroll
                for (int r = 0; r < 4; ++r)
                    qbf[base + (quad * 4 + r) * 16] =
                        __float2bfloat16((acc[t][u][r] + bl) * QSCALE);
            }
        } else if (mat == 1) {
            const int kq = (r0 >> 5) * 2048 + (nt >> 1) * 512 +
                           ((nt & 1) * 2 + (l16 >> 3)) * 128 + quad * 32 + (l16 & 7);
            #pragma unroll
            for (int u = 0; u < 2; ++u)
                #pragma unroll
                for (int r = 0; r < 4; ++r)
                    kbf[kq + u * 1024 + r * 8] = __float2bfloat16(acc[t][u][r] + bl);
        } else {
            #pragma unroll
            for (int u = 0; u < 2; ++u)
                #pragma unroll
                for (int r = 0; r < 4; ++r)
                    vbuf[(u * 16 + quad * 4 + r) * 66 + nt * 16 + l16] = acc[t][u][r] + bl;
        }
    }
    __syncthreads();

    // ---- V normalize phase (block-wide) ----
    const int rl = tid >> 3;
    const int jj = tid & 7;
    float ss = 0.f;
    #pragma unroll
    for (int i = 0; i < 8; ++i) {
        float x = vbuf[rl * 66 + jj * 8 + i];
        ss += x * x;
    }
    ss += __shfl_xor(ss, 1, 64);
    ss += __shfl_xor(ss, 2, 64);
    ss += __shfl_xor(ss, 4, 64);
    if (jj == 0) invb[rl] = rsqrtf(fmaxf(ss, 1e-24f));
    __syncthreads();
    float inv = invb[rl];
    bf16x8 vpk;
    #pragma unroll
    for (int i = 0; i < 8; ++i)
        vpk[i] = (__bf16)(vbuf[rl * 66 + jj * 8 + i] * inv);
    *(bf16x8*)(vnb + (size_t)(r0 + rl) * 64 + jj * 8) = vpk;

    const int tl = tid & 15;
    const int n  = (tid >> 4) & 3;
    const int s_ = tid >> 6;
    bf16x8 pack;
    #pragma unroll
    for (int j = 0; j < 8; ++j) {
        int key = s_ * 8 + j;
        pack[j] = (__bf16)(vbuf[key * 66 + n * 16 + tl] * invb[key]);
    }
    const int e1 = (r0 >> 5) * 2048 + (s_ >> 1) * 1024 + (n >> 1) * 512 +
                   (s_ & 1) * 256 + tl * 8 + (n & 1) * 4;
    bf16x4 plo = __builtin_shufflevector(pack, pack, 0, 1, 2, 3);
    bf16x4 phi = __builtin_shufflevector(pack, pack, 4, 5, 6, 7);
    *(bf16x4*)(vbf + e1)       = plo;
    *(bf16x4*)(vbf + e1 + 128) = phi;
}

// ---------------------------------------------------------------------------
// Kernel 2: attention. grid = 512 = qb(32) x bg(16); block = 256 q-rows x
// 512 keys; 2 blocks/CU. K/V LDS-staged, double buffered, lgkmcnt-only
// barriers (r14). No softmax denominator (r15: l2norm cancels it).
//
// ROUND 16: Opart partials stored BF16 (16 MB, was 32 MB f32). r2's
// counters showed the partial stream writes through to HBM (WRITE_SIZE
// 33 MB); halving it cuts the attn->finish round-trip ~8->4 MB/XCD.
// Error budget: bf16 partial quantization adds ~2-4e-4 to final absmax
// (measured 9.8e-4, threshold 2.45e-3 -> fits).
#define STAGE_W(BUF, KR, VR) do {                                            \
        *(float4*)((BUF) + stb) = KR;                                        \
        *(float4*)((BUF) + 4096 + stb) = VR; } while (0)
#define STAGE_L(KR, VR) do {                                                 \
        KR = *(const float4*)gk; VR = *(const float4*)gv;                    \
        gk += 4096; gv += 4096; } while (0)

#define BARRIER_KEEP_VMCNT() do {                                            \
        asm volatile("s_waitcnt lgkmcnt(0)" ::: "memory");                   \
        __builtin_amdgcn_s_barrier(); } while (0)

#define COMPUTE(BUF) do {                                                    \
    const char* kbp = (BUF);                                                 \
    const char* vbp = (BUF) + 4096;                                          \
    bf16x8 k00 = *(const bf16x8*)(kbp + lb);                                 \
    bf16x8 k01 = *(const bf16x8*)(kbp + lb + 1024);                          \
    bf16x8 k10 = *(const bf16x8*)(kbp + lb + 2048);                          \
    bf16x8 k11 = *(const bf16x8*)(kbp + lb + 3072);                          \
    s16x8 W0 = *(const s16x8*)(vbp + lb);                                    \
    s16x8 W1 = *(const s16x8*)(vbp + lb + 1024);                             \
    s16x8 W2 = *(const s16x8*)(vbp + lb + 2048);                             \
    s16x8 W3 = *(const s16x8*)(vbp + lb + 3072);                             \
    const f32x4 zero = (f32x4){0.f, 0.f, 0.f, 0.f};                          \
    _Pragma("unroll")                                                        \
    for (int u = 0; u < 4; ++u) {                                            \
        f32x4 s0 = mfma16(k00, qf32[u][0], zero);                            \
        s0       = mfma16(k01, qf32[u][1], s0);                              \
        f32x4 s1 = mfma16(k10, qf32[u][0], zero);                            \
        s1       = mfma16(k11, qf32[u][1], s1);                              \
        union { bf16x4 v; s16x4 s; } pf0, pf1;                               \
        _Pragma("unroll")                                                    \
        for (int r = 0; r < 4; ++r) {                                        \
            pf0.v[r] = (__bf16)__builtin_amdgcn_exp2f(s0[r]);                \
            pf1.v[r] = (__bf16)__builtin_amdgcn_exp2f(s1[r]);                \
        }                                                                    \
        of[u][0] = mfma1k(pf0.s, vlo(W0), of[u][0]);                         \
        of[u][0] = mfma1k(pf1.s, vlo(W2), of[u][0]);                         \
        of[u][1] = mfma1k(pf0.s, vhi(W0), of[u][1]);                         \
        of[u][1] = mfma1k(pf1.s, vhi(W2), of[u][1]);                         \
        of[u][2] = mfma1k(pf0.s, vlo(W1), of[u][2]);                         \
        of[u][2] = mfma1k(pf1.s, vlo(W3), of[u][2]);                         \
        of[u][3] = mfma1k(pf0.s, vhi(W1), of[u][3]);                         \
        of[u][3] = mfma1k(pf1.s, vhi(W3), of[u][3]);                         \
    } } while (0)

__global__ __launch_bounds__(256, 2) void attn_kernel(
    const __hip_bfloat16* __restrict__ qbf,
    const __hip_bfloat16* __restrict__ kbf,
    const __hip_bfloat16* __restrict__ vbf,
    __hip_bfloat16* __restrict__ Opart,
    float* __restrict__ outz)
{
    __shared__ __align__(16) char pool[16384];
    char* bufA = pool;
    char* bufB = pool + 8192;

    const int tid = threadIdx.x;
    if (blockIdx.x == 0) {
        #pragma unroll
        for (int z = 0; z < 4; ++z)
            ((float4*)outz)[tid * 4 + z] = (float4){0.f, 0.f, 0.f, 0.f};
    }

    const int w    = tid >> 6;
    const int lane = tid & 63;
    const int l16  = lane & 15;
    const int quad = lane >> 4;
    const int qb   = blockIdx.x >> 4;
    const int bg   = blockIdx.x & 15;
    const int r0   = qb * 256 + w * 64;               // 64 q-rows per wave
    const int fo32 = l16 * 16 + (quad & 1) * 8;
    const int qh   = quad >> 1;
    const int lb   = lane * 16;
    const int stb  = tid * 16;

    bf16x8 qf32[4][2];
    #pragma unroll
    for (int u = 0; u < 4; ++u)
        #pragma unroll
        for (int p = 0; p < 2; ++p)
            qf32[u][p] = *(const bf16x8*)(qbf +
                ((((r0 >> 4) + u) * 4 + p * 2 + qh) << 8) + fo32);

    f32x4 of[4][4];
    #pragma unroll
    for (int u = 0; u < 4; ++u)
        #pragma unroll
        for (int n = 0; n < 4; ++n)
            of[u][n] = (f32x4){0.f, 0.f, 0.f, 0.f};

    const char* gk = (const char*)kbf + (size_t)(bg * 16) * 4096 + stb;
    const char* gv = (const char*)vbf + (size_t)(bg * 16) * 4096 + stb;

    float4 ka, va, kb_, vb_;
    STAGE_L(ka, va);
    STAGE_W(bufA, ka, va);
    STAGE_L(kb_, vb_);
    BARRIER_KEEP_VMCNT();                             // bufA ready

    #pragma unroll 1
    for (int body = 0; body < 7; ++body) {
        STAGE_W(bufB, kb_, vb_);
        STAGE_L(ka, va);
        COMPUTE(bufA);
        BARRIER_KEEP_VMCNT();
        STAGE_W(bufA, ka, va);
        STAGE_L(kb_, vb_);
        COMPUTE(bufB);
        BARRIER_KEEP_VMCNT();
    }
    STAGE_W(bufB, kb_, vb_);
    COMPUTE(bufA);
    BARRIER_KEEP_VMCNT();
    COMPUTE(bufB);

    // row-major-partials store: Opart[row][bg][64] in BF16 (unnormalized)
    #pragma unroll
    for (int u = 0; u < 4; ++u)
        #pragma unroll
        for (int n = 0; n < 4; ++n)
            #pragma unroll
            for (int r = 0; r < 4; ++r)
                Opart[((size_t)(r0 + u * 16 + quad * 4 + r) * 16 + bg) * 64
                      + n * 16 + l16] = __float2bfloat16(of[u][n][r]);
}

// ---------------------------------------------------------------------------
// Kernel 3: FUSED combine + sim. grid = 256 blocks x 256 thr:
// block = (a, jhalf); a = bid>>1 is the contraction slice, jhalf = bid&1
// the 32-row half of Qn this block normalizes/multiplies. Phase 1: sum 16
// bf16 partials/row (one bf16x8 load per partial), l2-normalize (no lsum:
// cancels), bf16 -> LDS qn. Phase 2: 4 waves, K=64 folded in-register,
// atomicAdd into out (zeroed by attn block 0).
__global__ __launch_bounds__(256) void finish_kernel(
    const __hip_bfloat16* __restrict__ Opart,
    const __hip_bfloat16* __restrict__ vnb,
    float* __restrict__ out)
{
    __shared__ __hip_bfloat16 qn[32][68];

    const int a     = blockIdx.x >> 1;                // 0..127
    const int jhalf = blockIdx.x & 1;
    const int tid   = threadIdx.x;                    // 0..255

    // ---- phase 1: 8 threads per row (8 cols each), 32 rows ----
    {
        const int bl = tid >> 3;                      // 0..31 local row
        const int c8 = tid & 7;
        const int r  = (jhalf * 32 + bl) * 128 + a;
        float acc[8] = {0.f, 0.f, 0.f, 0.f, 0.f, 0.f, 0.f, 0.f};
        #pragma unroll
        for (int g = 0; g < 16; ++g) {
            bf16x8 t = *(const bf16x8*)(Opart +
                ((size_t)r * 16 + g) * 64 + c8 * 8);
            #pragma unroll
            for (int c = 0; c < 8; ++c)
                acc[c] += (float)t[c];
        }
        // no lsum: l2norm(O/l) == l2norm(O)
        float ss = 0.f;
        #pragma unroll
        for (int c = 0; c < 8; ++c)
            ss += acc[c] * acc[c];
        ss += __shfl_xor(ss, 1, 64);
        ss += __shfl_xor(ss, 2, 64);
        ss += __shfl_xor(ss, 4, 64);
        const float inv = rsqrtf(fmaxf(ss, 1e-24f));
        bf16x8 pk;
        #pragma unroll
        for (int c = 0; c < 8; ++c)
            pk[c] = (__bf16)(acc[c] * inv);
        *(bf16x8*)&qn[bl][c8 * 8] = pk;
    }
    __syncthreads();

    // ---- phase 2: GEMM, 4 waves = mi(4); K=64 folded in-register ----
    {
        const int w    = tid >> 6;                    // mi = 0..3
        const int lane = tid & 63;
        const int l16  = lane & 15;
        const int quad = lane >> 4;

        f32x4 accd[2];
        accd[0] = (f32x4){0.f, 0.f, 0.f, 0.f};
        accd[1] = (f32x4){0.f, 0.f, 0.f, 0.f};
        #pragma unroll
        for (int ks = 0; ks < 2; ++ks) {
            const int dq = ks * 32 + quad * 8;
            bf16x8 af = *(const bf16x8*)(vnb +
                (size_t)(w * 16 + l16) * 8192 + a * 64 + dq);
            #pragma unroll
            for (int ni = 0; ni < 2; ++ni) {
                bf16x8 bfv = *(const bf16x8*)&qn[ni * 16 + l16][dq];
                accd[ni] = mfma16(af, bfv, accd[ni]);
            }
        }
        #pragma unroll
        for (int ni = 0; ni < 2; ++ni)
            #pragma unroll
            for (int r = 0; r < 4; ++r)
                atomicAdd(&out[(w * 16 + quad * 4 + r) * 64 +
                               jhalf * 32 + ni * 16 + l16],
                          accd[ni][r] * (1.f / 128.f));
    }
}

// ---------------------------------------------------------------------------
extern "C" void kernel_launch(void* const* d_in, const int* in_sizes, int n_in,
                              void* d_out, int out_size, void* d_ws, size_t ws_size,
                              hipStream_t stream)
{
    const float* feat = (const float*)d_in[0];
    const float* Wq   = (const float*)d_in[1];
    const float* bq   = (const float*)d_in[2];
    const float* Wk   = (const float*)d_in[3];
    const float* bk   = (const float*)d_in[4];
    const float* Wv   = (const float*)d_in[5];
    const float* bv   = (const float*)d_in[6];
    float* out = (float*)d_out;

    const size_t MB = 1u << 20;
    char* ws = (char*)d_ws;
    __hip_bfloat16* qbf = (__hip_bfloat16*)(ws);              // 1 MB (frag-tiled, pre-scaled)
    __hip_bfloat16* kbf = (__hip_bfloat16*)(ws + 1 * MB);     // 1 MB (fragment-linear)
    __hip_bfloat16* vbf = (__hip_bfloat16*)(ws + 2 * MB);     // 1 MB (fragment-linear)
    __hip_bfloat16* vnb = (__hip_bfloat16*)(ws + 3 * MB);     // 1 MB (row-major)
    __hip_bfloat16* Opart = (__hip_bfloat16*)(ws + 4 * MB);   // 16 MB (8192 x 16 x 64 bf16)

    proj_kernel<<<256, 256, 0, stream>>>(feat, Wq, bq, Wk, bk, Wv, bv,
                                         qbf, kbf, vbf, vnb);
    attn_kernel<<<512, 256, 0, stream>>>(qbf, kbf, vbf, Opart, out);
    finish_kernel<<<256, 256, 0, stream>>>(Opart, vnb, out);
}

// Round 17
// 105.681 us; speedup vs baseline: 1.1586x; 1.0005x over previous
//
#include <hip/hip_runtime.h>
#include <hip/hip_bf16.h>

#define NROW 8192   // B*A = 64*128
#define INC  128
#define OUTC 64
#define BG   16     // key-split factor

// Q is pre-scaled by log2(e)/sqrt(64) at projection time, so attention
// computes p = exp2(q'.k) with a single v_exp_f32 per score.
#define QSCALE 0.18033688011112042f

typedef __bf16 bf16x8 __attribute__((ext_vector_type(8)));
typedef __bf16 bf16x4 __attribute__((ext_vector_type(4)));
typedef short  s16x4  __attribute__((ext_vector_type(4)));
typedef short  s16x8  __attribute__((ext_vector_type(8)));
typedef float  f32x4  __attribute__((ext_vector_type(4)));

static __device__ __forceinline__ f32x4 mfma16(bf16x8 a, bf16x8 b, f32x4 c) {
    return __builtin_amdgcn_mfma_f32_16x16x32_bf16(a, b, c, 0, 0, 0);
}
// 16x16x16 bf16 (K=16). C/D of S^T IS the A-operand layout of P for PV.
static __device__ __forceinline__ f32x4 mfma1k(s16x4 a, s16x4 b, f32x4 c) {
    return __builtin_amdgcn_mfma_f32_16x16x16bf16_1k(a, b, c, 0, 0, 0);
}

static __device__ __forceinline__ bf16x8 cvt8(float4 lo, float4 hi) {
    bf16x8 r;
    r[0] = (__bf16)lo.x; r[1] = (__bf16)lo.y; r[2] = (__bf16)lo.z; r[3] = (__bf16)lo.w;
    r[4] = (__bf16)hi.x; r[5] = (__bf16)hi.y; r[6] = (__bf16)hi.z; r[7] = (__bf16)hi.w;
    return r;
}
static __device__ __forceinline__ s16x4 vlo(s16x8 x) {
    return __builtin_shufflevector(x, x, 0, 1, 2, 3);
}
static __device__ __forceinline__ s16x4 vhi(s16x8 x) {
    return __builtin_shufflevector(x, x, 4, 5, 6, 7);
}

// ---------------------------------------------------------------------------
// Kernel 1: projection via MFMA. grid = 256 = b(64) x aq(4), 1 block/CU.
// Slab staged once; 12 n-tiles (3 mats x 4) spread 3-per-wave. qbf is
// frag-tiled + pre-scaled; kbf/vbf fragment-linear (attn LDS staging is a
// linear tid*16 copy, ds_read_b128 conflict-free); vnb row-major normalized.
__global__ __launch_bounds__(256) void proj_kernel(
    const float* __restrict__ feat,
    const float* __restrict__ Wq, const float* __restrict__ bq,
    const float* __restrict__ Wk, const float* __restrict__ bk,
    const float* __restrict__ Wv, const float* __restrict__ bv,
    __hip_bfloat16* __restrict__ qbf, __hip_bfloat16* __restrict__ kbf,
    __hip_bfloat16* __restrict__ vbf, __hip_bfloat16* __restrict__ vnb)
{
    __shared__ float slab[32 * 132];
    __shared__ float vbuf[32 * 66];
    __shared__ float invb[32];

    const int tid = threadIdx.x;
    const int w    = tid >> 6;
    const int lane = tid & 63;
    const int l16  = lane & 15;
    const int quad = lane >> 4;

    const int b   = blockIdx.x >> 2;
    const int a0  = (blockIdx.x & 3) * 32;
    const int r0  = b * 128 + a0;
    const float* fb = feat + (size_t)b * INC * 128;

    for (int i = tid; i < 32 * 128; i += 256) {
        int c = i >> 5, a = i & 31;
        slab[a * 132 + c] = fb[c * 128 + a0 + a];
    }
    __syncthreads();

    f32x4 acc[3][2];
    #pragma unroll
    for (int t = 0; t < 3; ++t)
        #pragma unroll
        for (int u = 0; u < 2; ++u)
            acc[t][u] = (f32x4){0.f, 0.f, 0.f, 0.f};

    #pragma unroll
    for (int kc = 0; kc < 4; ++kc) {
        const int k0 = kc * 32 + quad * 8;
        bf16x8 afr[2];
        #pragma unroll
        for (int u = 0; u < 2; ++u) {
            const float* ar = slab + (u * 16 + l16) * 132 + k0;
            afr[u] = cvt8(*(const float4*)ar, *(const float4*)(ar + 4));
        }
        #pragma unroll
        for (int t = 0; t < 3; ++t) {
            const int tile = w * 3 + t;
            const int mat  = tile >> 2;
            const float* W = (mat == 0) ? Wq : (mat == 1) ? Wk : Wv;
            const float* wr = W + ((tile & 3) * 16 + l16) * INC + k0;
            bf16x8 bfr = cvt8(*(const float4*)wr, *(const float4*)(wr + 4));
            #pragma unroll
            for (int u = 0; u < 2; ++u)
                acc[t][u] = mfma16(afr[u], bfr, acc[t][u]);
        }
    }

    #pragma unroll
    for (int t = 0; t < 3; ++t) {
        const int tile = w * 3 + t;
        const int mat  = tile >> 2;
        const int nt   = tile & 3;
        const float* bias = (mat == 0) ? bq : (mat == 1) ? bk : bv;
        const float bl = bias[nt * 16 + l16];
        if (mat == 0) {
            #pragma unroll
            for (int u = 0; u < 2; ++u) {
                const int base = ((((r0 >> 4) + u) * 4 + nt) << 8) + l16;
                #pragma unroll
                for (int r = 0; r < 4; ++r)
                    qbf[base + (quad * 4 + r) * 16] =
                        __float2bfloat16((acc[t][u][r] + bl) * QSCALE);
            }
        } else if (mat == 1) {
            const int kq = (r0 >> 5) * 2048 + (nt >> 1) * 512 +
                           ((nt & 1) * 2 + (l16 >> 3)) * 128 + quad * 32 + (l16 & 7);
            #pragma unroll
            for (int u = 0; u < 2; ++u)
                #pragma unroll
                for (int r = 0; r < 4; ++r)
                    kbf[kq + u * 1024 + r * 8] = __float2bfloat16(acc[t][u][r] + bl);
        } else {
            #pragma unroll
            for (int u = 0; u < 2; ++u)
                #pragma unroll
                for (int r = 0; r < 4; ++r)
                    vbuf[(u * 16 + quad * 4 + r) * 66 + nt * 16 + l16] = acc[t][u][r] + bl;
        }
    }
    __syncthreads();

    // ---- V normalize phase (block-wide) ----
    const int rl = tid >> 3;
    const int jj = tid & 7;
    float ss = 0.f;
    #pragma unroll
    for (int i = 0; i < 8; ++i) {
        float x = vbuf[rl * 66 + jj * 8 + i];
        ss += x * x;
    }
    ss += __shfl_xor(ss, 1, 64);
    ss += __shfl_xor(ss, 2, 64);
    ss += __shfl_xor(ss, 4, 64);
    if (jj == 0) invb[rl] = rsqrtf(fmaxf(ss, 1e-24f));
    __syncthreads();
    float inv = invb[rl];
    bf16x8 vpk;
    #pragma unroll
    for (int i = 0; i < 8; ++i)
        vpk[i] = (__bf16)(vbuf[rl * 66 + jj * 8 + i] * inv);
    *(bf16x8*)(vnb + (size_t)(r0 + rl) * 64 + jj * 8) = vpk;

    const int tl = tid & 15;
    const int n  = (tid >> 4) & 3;
    const int s_ = tid >> 6;
    bf16x8 pack;
    #pragma unroll
    for (int j = 0; j < 8; ++j) {
        int key = s_ * 8 + j;
        pack[j] = (__bf16)(vbuf[key * 66 + n * 16 + tl] * invb[key]);
    }
    const int e1 = (r0 >> 5) * 2048 + (s_ >> 1) * 1024 + (n >> 1) * 512 +
                   (s_ & 1) * 256 + tl * 8 + (n & 1) * 4;
    bf16x4 plo = __builtin_shufflevector(pack, pack, 0, 1, 2, 3);
    bf16x4 phi = __builtin_shufflevector(pack, pack, 4, 5, 6, 7);
    *(bf16x4*)(vbf + e1)       = plo;
    *(bf16x4*)(vbf + e1 + 128) = phi;
}

// ---------------------------------------------------------------------------
// Kernel 2: attention. ROUND 17: grid = 1024 = qb(64) x bg(16); block =
// 128 q-rows x 512 keys; 32 q-rows/wave (u=2); __launch_bounds__(256,4)
// -> 4 blocks/CU = 4 waves/SIMD, the one occupancy cell never measured
// with LDS-staged K/V (live set ~100 regs < 128 cap, no spill; LDS
// 4x16KB = 64KB < 160KB). If attn's ~80%-idle is exposed memory latency,
// doubling resident waves halves the exposure. + s_setprio(1) around the
// MFMA/VALU cluster (T5; phase-split structure exists now). Opart layout
// and totals unchanged (absolute-row indexed).
#define STAGE_W(BUF, KR, VR) do {                                            \
        *(float4*)((BUF) + stb) = KR;                                        \
        *(float4*)((BUF) + 4096 + stb) = VR; } while (0)
#define STAGE_L(KR, VR) do {                                                 \
        KR = *(const float4*)gk; VR = *(const float4*)gv;                    \
        gk += 4096; gv += 4096; } while (0)

#define BARRIER_KEEP_VMCNT() do {                                            \
        asm volatile("s_waitcnt lgkmcnt(0)" ::: "memory");                   \
        __builtin_amdgcn_s_barrier(); } while (0)

#define COMPUTE(BUF) do {                                                    \
    const char* kbp = (BUF);                                                 \
    const char* vbp = (BUF) + 4096;                                          \
    bf16x8 k00 = *(const bf16x8*)(kbp + lb);                                 \
    bf16x8 k01 = *(const bf16x8*)(kbp + lb + 1024);                          \
    bf16x8 k10 = *(const bf16x8*)(kbp + lb + 2048);                          \
    bf16x8 k11 = *(const bf16x8*)(kbp + lb + 3072);                          \
    s16x8 W0 = *(const s16x8*)(vbp + lb);                                    \
    s16x8 W1 = *(const s16x8*)(vbp + lb + 1024);                             \
    s16x8 W2 = *(const s16x8*)(vbp + lb + 2048);                             \
    s16x8 W3 = *(const s16x8*)(vbp + lb + 3072);                             \
    const f32x4 zero = (f32x4){0.f, 0.f, 0.f, 0.f};                          \
    __builtin_amdgcn_s_setprio(1);                                           \
    _Pragma("unroll")                                                        \
    for (int u = 0; u < 2; ++u) {                                            \
        f32x4 s0 = mfma16(k00, qf32[u][0], zero);                            \
        s0       = mfma16(k01, qf32[u][1], s0);                              \
        f32x4 s1 = mfma16(k10, qf32[u][0], zero);                            \
        s1       = mfma16(k11, qf32[u][1], s1);                              \
        union { bf16x4 v; s16x4 s; } pf0, pf1;                               \
        _Pragma("unroll")                                                    \
        for (int r = 0; r < 4; ++r) {                                        \
            pf0.v[r] = (__bf16)__builtin_amdgcn_exp2f(s0[r]);                \
            pf1.v[r] = (__bf16)__builtin_amdgcn_exp2f(s1[r]);                \
        }                                                                    \
        of[u][0] = mfma1k(pf0.s, vlo(W0), of[u][0]);                         \
        of[u][0] = mfma1k(pf1.s, vlo(W2), of[u][0]);                         \
        of[u][1] = mfma1k(pf0.s, vhi(W0), of[u][1]);                         \
        of[u][1] = mfma1k(pf1.s, vhi(W2), of[u][1]);                         \
        of[u][2] = mfma1k(pf0.s, vlo(W1), of[u][2]);                         \
        of[u][2] = mfma1k(pf1.s, vlo(W3), of[u][2]);                         \
        of[u][3] = mfma1k(pf0.s, vhi(W1), of[u][3]);                         \
        of[u][3] = mfma1k(pf1.s, vhi(W3), of[u][3]);                         \
    }                                                                        \
    __builtin_amdgcn_s_setprio(0);                                           \
    } while (0)

__global__ __launch_bounds__(256, 4) void attn_kernel(
    const __hip_bfloat16* __restrict__ qbf,
    const __hip_bfloat16* __restrict__ kbf,
    const __hip_bfloat16* __restrict__ vbf,
    __hip_bfloat16* __restrict__ Opart,
    float* __restrict__ outz)
{
    __shared__ __align__(16) char pool[16384];
    char* bufA = pool;
    char* bufB = pool + 8192;

    const int tid = threadIdx.x;
    if (blockIdx.x == 0) {
        #pragma unroll
        for (int z = 0; z < 4; ++z)
            ((float4*)outz)[tid * 4 + z] = (float4){0.f, 0.f, 0.f, 0.f};
    }

    const int w    = tid >> 6;
    const int lane = tid & 63;
    const int l16  = lane & 15;
    const int quad = lane >> 4;
    const int qb   = blockIdx.x >> 4;                 // 0..63
    const int bg   = blockIdx.x & 15;
    const int r0   = qb * 128 + w * 32;               // 32 q-rows per wave
    const int fo32 = l16 * 16 + (quad & 1) * 8;
    const int qh   = quad >> 1;
    const int lb   = lane * 16;
    const int stb  = tid * 16;

    bf16x8 qf32[2][2];
    #pragma unroll
    for (int u = 0; u < 2; ++u)
        #pragma unroll
        for (int p = 0; p < 2; ++p)
            qf32[u][p] = *(const bf16x8*)(qbf +
                ((((r0 >> 4) + u) * 4 + p * 2 + qh) << 8) + fo32);

    f32x4 of[2][4];
    #pragma unroll
    for (int u = 0; u < 2; ++u)
        #pragma unroll
        for (int n = 0; n < 4; ++n)
            of[u][n] = (f32x4){0.f, 0.f, 0.f, 0.f};

    const char* gk = (const char*)kbf + (size_t)(bg * 16) * 4096 + stb;
    const char* gv = (const char*)vbf + (size_t)(bg * 16) * 4096 + stb;

    float4 ka, va, kb_, vb_;
    STAGE_L(ka, va);
    STAGE_W(bufA, ka, va);
    STAGE_L(kb_, vb_);
    BARRIER_KEEP_VMCNT();                             // bufA ready

    #pragma unroll 1
    for (int body = 0; body < 7; ++body) {
        STAGE_W(bufB, kb_, vb_);
        STAGE_L(ka, va);
        COMPUTE(bufA);
        BARRIER_KEEP_VMCNT();
        STAGE_W(bufA, ka, va);
        STAGE_L(kb_, vb_);
        COMPUTE(bufB);
        BARRIER_KEEP_VMCNT();
    }
    STAGE_W(bufB, kb_, vb_);
    COMPUTE(bufA);
    BARRIER_KEEP_VMCNT();
    COMPUTE(bufB);

    // row-major-partials store: Opart[row][bg][64] in BF16 (unnormalized)
    #pragma unroll
    for (int u = 0; u < 2; ++u)
        #pragma unroll
        for (int n = 0; n < 4; ++n)
            #pragma unroll
            for (int r = 0; r < 4; ++r)
                Opart[((size_t)(r0 + u * 16 + quad * 4 + r) * 16 + bg) * 64
                      + n * 16 + l16] = __float2bfloat16(of[u][n][r]);
}

// ---------------------------------------------------------------------------
// Kernel 3: FUSED combine + sim. grid = 256 blocks x 256 thr:
// block = (a, jhalf); a = bid>>1 is the contraction slice, jhalf = bid&1
// the 32-row half of Qn this block normalizes/multiplies. Phase 1: sum 16
// bf16 partials/row (one bf16x8 load per partial), l2-normalize (no lsum:
// cancels), bf16 -> LDS qn. Phase 2: 4 waves, K=64 folded in-register,
// atomicAdd into out (zeroed by attn block 0).
__global__ __launch_bounds__(256) void finish_kernel(
    const __hip_bfloat16* __restrict__ Opart,
    const __hip_bfloat16* __restrict__ vnb,
    float* __restrict__ out)
{
    __shared__ __hip_bfloat16 qn[32][68];

    const int a     = blockIdx.x >> 1;                // 0..127
    const int jhalf = blockIdx.x & 1;
    const int tid   = threadIdx.x;                    // 0..255

    // ---- phase 1: 8 threads per row (8 cols each), 32 rows ----
    {
        const int bl = tid >> 3;                      // 0..31 local row
        const int c8 = tid & 7;
        const int r  = (jhalf * 32 + bl) * 128 + a;
        float acc[8] = {0.f, 0.f, 0.f, 0.f, 0.f, 0.f, 0.f, 0.f};
        #pragma unroll
        for (int g = 0; g < 16; ++g) {
            bf16x8 t = *(const bf16x8*)(Opart +
                ((size_t)r * 16 + g) * 64 + c8 * 8);
            #pragma unroll
            for (int c = 0; c < 8; ++c)
                acc[c] += (float)t[c];
        }
        // no lsum: l2norm(O/l) == l2norm(O)
        float ss = 0.f;
        #pragma unroll
        for (int c = 0; c < 8; ++c)
            ss += acc[c] * acc[c];
        ss += __shfl_xor(ss, 1, 64);
        ss += __shfl_xor(ss, 2, 64);
        ss += __shfl_xor(ss, 4, 64);
        const float inv = rsqrtf(fmaxf(ss, 1e-24f));
        bf16x8 pk;
        #pragma unroll
        for (int c = 0; c < 8; ++c)
            pk[c] = (__bf16)(acc[c] * inv);
        *(bf16x8*)&qn[bl][c8 * 8] = pk;
    }
    __syncthreads();

    // ---- phase 2: GEMM, 4 waves = mi(4); K=64 folded in-register ----
    {
        const int w    = tid >> 6;                    // mi = 0..3
        const int lane = tid & 63;
        const int l16  = lane & 15;
        const int quad = lane >> 4;

        f32x4 accd[2];
        accd[0] = (f32x4){0.f, 0.f, 0.f, 0.f};
        accd[1] = (f32x4){0.f, 0.f, 0.f, 0.f};
        #pragma unroll
        for (int ks = 0; ks < 2; ++ks) {
            const int dq = ks * 32 + quad * 8;
            bf16x8 af = *(const bf16x8*)(vnb +
                (size_t)(w * 16 + l16) * 8192 + a * 64 + dq);
            #pragma unroll
            for (int ni = 0; ni < 2; ++ni) {
                bf16x8 bfv = *(const bf16x8*)&qn[ni * 16 + l16][dq];
                accd[ni] = mfma16(af, bfv, accd[ni]);
            }
        }
        #pragma unroll
        for (int ni = 0; ni < 2; ++ni)
            #pragma unroll
            for (int r = 0; r < 4; ++r)
                atomicAdd(&out[(w * 16 + quad * 4 + r) * 64 +
                               jhalf * 32 + ni * 16 + l16],
                          accd[ni][r] * (1.f / 128.f));
    }
}

// ---------------------------------------------------------------------------
extern "C" void kernel_launch(void* const* d_in, const int* in_sizes, int n_in,
                              void* d_out, int out_size, void* d_ws, size_t ws_size,
                              hipStream_t stream)
{
    const float* feat = (const float*)d_in[0];
    const float* Wq   = (const float*)d_in[1];
    const float* bq   = (const float*)d_in[2];
    const float* Wk   = (const float*)d_in[3];
    const float* bk   = (const float*)d_in[4];
    const float* Wv   = (const float*)d_in[5];
    const float* bv   = (const float*)d_in[6];
    float* out = (float*)d_out;

    const size_t MB = 1u << 20;
    char* ws = (char*)d_ws;
    __hip_bfloat16* qbf = (__hip_bfloat16*)(ws);              // 1 MB (frag-tiled, pre-scaled)
    __hip_bfloat16* kbf = (__hip_bfloat16*)(ws + 1 * MB);     // 1 MB (fragment-linear)
    __hip_bfloat16* vbf = (__hip_bfloat16*)(ws + 2 * MB);     // 1 MB (fragment-linear)
    __hip_bfloat16* vnb = (__hip_bfloat16*)(ws + 3 * MB);     // 1 MB (row-major)
    __hip_bfloat16* Opart = (__hip_bfloat16*)(ws + 4 * MB);   // 16 MB (8192 x 16 x 64 bf16)

    proj_kernel<<<256, 256, 0, stream>>>(feat, Wq, bq, Wk, bk, Wv, bv,
                                         qbf, kbf, vbf, vnb);
    attn_kernel<<<1024, 256, 0, stream>>>(qbf, kbf, vbf, Opart, out);
    finish_kernel<<<256, 256, 0, stream>>>(Opart, vnb, out);
}

// Round 18
// 102.766 us; speedup vs baseline: 1.1915x; 1.0284x over previous
//
#include <hip/hip_runtime.h>
#include <hip/hip_bf16.h>

#define NROW 8192   // B*A = 64*128
#define INC  128
#define OUTC 64
#define BG   8      // key-split factor (r18: halved -> half the partial traffic)

// Q is pre-scaled by log2(e)/sqrt(64) at projection time, so attention
// computes p = exp2(q'.k) with a single v_exp_f32 per score.
#define QSCALE 0.18033688011112042f

typedef __bf16 bf16x8 __attribute__((ext_vector_type(8)));
typedef __bf16 bf16x4 __attribute__((ext_vector_type(4)));
typedef short  s16x4  __attribute__((ext_vector_type(4)));
typedef short  s16x8  __attribute__((ext_vector_type(8)));
typedef float  f32x4  __attribute__((ext_vector_type(4)));

static __device__ __forceinline__ f32x4 mfma16(bf16x8 a, bf16x8 b, f32x4 c) {
    return __builtin_amdgcn_mfma_f32_16x16x32_bf16(a, b, c, 0, 0, 0);
}
// 16x16x16 bf16 (K=16). C/D of S^T IS the A-operand layout of P for PV.
static __device__ __forceinline__ f32x4 mfma1k(s16x4 a, s16x4 b, f32x4 c) {
    return __builtin_amdgcn_mfma_f32_16x16x16bf16_1k(a, b, c, 0, 0, 0);
}

static __device__ __forceinline__ bf16x8 cvt8(float4 lo, float4 hi) {
    bf16x8 r;
    r[0] = (__bf16)lo.x; r[1] = (__bf16)lo.y; r[2] = (__bf16)lo.z; r[3] = (__bf16)lo.w;
    r[4] = (__bf16)hi.x; r[5] = (__bf16)hi.y; r[6] = (__bf16)hi.z; r[7] = (__bf16)hi.w;
    return r;
}
static __device__ __forceinline__ s16x4 vlo(s16x8 x) {
    return __builtin_shufflevector(x, x, 0, 1, 2, 3);
}
static __device__ __forceinline__ s16x4 vhi(s16x8 x) {
    return __builtin_shufflevector(x, x, 4, 5, 6, 7);
}

// ---------------------------------------------------------------------------
// Kernel 1: projection via MFMA. grid = 256 = b(64) x aq(4), 1 block/CU.
// Slab staged once; 12 n-tiles (3 mats x 4) spread 3-per-wave. qbf is
// frag-tiled + pre-scaled; kbf/vbf fragment-linear (attn LDS staging is a
// linear tid*16 copy, ds_read_b128 conflict-free); vnb row-major normalized.
__global__ __launch_bounds__(256) void proj_kernel(
    const float* __restrict__ feat,
    const float* __restrict__ Wq, const float* __restrict__ bq,
    const float* __restrict__ Wk, const float* __restrict__ bk,
    const float* __restrict__ Wv, const float* __restrict__ bv,
    __hip_bfloat16* __restrict__ qbf, __hip_bfloat16* __restrict__ kbf,
    __hip_bfloat16* __restrict__ vbf, __hip_bfloat16* __restrict__ vnb)
{
    __shared__ float slab[32 * 132];
    __shared__ float vbuf[32 * 66];
    __shared__ float invb[32];

    const int tid = threadIdx.x;
    const int w    = tid >> 6;
    const int lane = tid & 63;
    const int l16  = lane & 15;
    const int quad = lane >> 4;

    const int b   = blockIdx.x >> 2;
    const int a0  = (blockIdx.x & 3) * 32;
    const int r0  = b * 128 + a0;
    const float* fb = feat + (size_t)b * INC * 128;

    for (int i = tid; i < 32 * 128; i += 256) {
        int c = i >> 5, a = i & 31;
        slab[a * 132 + c] = fb[c * 128 + a0 + a];
    }
    __syncthreads();

    f32x4 acc[3][2];
    #pragma unroll
    for (int t = 0; t < 3; ++t)
        #pragma unroll
        for (int u = 0; u < 2; ++u)
            acc[t][u] = (f32x4){0.f, 0.f, 0.f, 0.f};

    #pragma unroll
    for (int kc = 0; kc < 4; ++kc) {
        const int k0 = kc * 32 + quad * 8;
        bf16x8 afr[2];
        #pragma unroll
        for (int u = 0; u < 2; ++u) {
            const float* ar = slab + (u * 16 + l16) * 132 + k0;
            afr[u] = cvt8(*(const float4*)ar, *(const float4*)(ar + 4));
        }
        #pragma unroll
        for (int t = 0; t < 3; ++t) {
            const int tile = w * 3 + t;
            const int mat  = tile >> 2;
            const float* W = (mat == 0) ? Wq : (mat == 1) ? Wk : Wv;
            const float* wr = W + ((tile & 3) * 16 + l16) * INC + k0;
            bf16x8 bfr = cvt8(*(const float4*)wr, *(const float4*)(wr + 4));
            #pragma unroll
            for (int u = 0; u < 2; ++u)
                acc[t][u] = mfma16(afr[u], bfr, acc[t][u]);
        }
    }

    #pragma unroll
    for (int t = 0; t < 3; ++t) {
        const int tile = w * 3 + t;
        const int mat  = tile >> 2;
        const int nt   = tile & 3;
        const float* bias = (mat == 0) ? bq : (mat == 1) ? bk : bv;
        const float bl = bias[nt * 16 + l16];
        if (mat == 0) {
            #pragma unroll
            for (int u = 0; u < 2; ++u) {
                const int base = ((((r0 >> 4) + u) * 4 + nt) << 8) + l16;
                #pragma unroll
                for (int r = 0; r < 4; ++r)
                    qbf[base + (quad * 4 + r) * 16] =
                        __float2bfloat16((acc[t][u][r] + bl) * QSCALE);
            }
        } else if (mat == 1) {
            const int kq = (r0 >> 5) * 2048 + (nt >> 1) * 512 +
                           ((nt & 1) * 2 + (l16 >> 3)) * 128 + quad * 32 + (l16 & 7);
            #pragma unroll
            for (int u = 0; u < 2; ++u)
                #pragma unroll
                for (int r = 0; r < 4; ++r)
                    kbf[kq + u * 1024 + r * 8] = __float2bfloat16(acc[t][u][r] + bl);
        } else {
            #pragma unroll
            for (int u = 0; u < 2; ++u)
                #pragma unroll
                for (int r = 0; r < 4; ++r)
                    vbuf[(u * 16 + quad * 4 + r) * 66 + nt * 16 + l16] = acc[t][u][r] + bl;
        }
    }
    __syncthreads();

    // ---- V normalize phase (block-wide) ----
    const int rl = tid >> 3;
    const int jj = tid & 7;
    float ss = 0.f;
    #pragma unroll
    for (int i = 0; i < 8; ++i) {
        float x = vbuf[rl * 66 + jj * 8 + i];
        ss += x * x;
    }
    ss += __shfl_xor(ss, 1, 64);
    ss += __shfl_xor(ss, 2, 64);
    ss += __shfl_xor(ss, 4, 64);
    if (jj == 0) invb[rl] = rsqrtf(fmaxf(ss, 1e-24f));
    __syncthreads();
    float inv = invb[rl];
    bf16x8 vpk;
    #pragma unroll
    for (int i = 0; i < 8; ++i)
        vpk[i] = (__bf16)(vbuf[rl * 66 + jj * 8 + i] * inv);
    *(bf16x8*)(vnb + (size_t)(r0 + rl) * 64 + jj * 8) = vpk;

    const int tl = tid & 15;
    const int n  = (tid >> 4) & 3;
    const int s_ = tid >> 6;
    bf16x8 pack;
    #pragma unroll
    for (int j = 0; j < 8; ++j) {
        int key = s_ * 8 + j;
        pack[j] = (__bf16)(vbuf[key * 66 + n * 16 + tl] * invb[key]);
    }
    const int e1 = (r0 >> 5) * 2048 + (s_ >> 1) * 1024 + (n >> 1) * 512 +
                   (s_ & 1) * 256 + tl * 8 + (n & 1) * 4;
    bf16x4 plo = __builtin_shufflevector(pack, pack, 0, 1, 2, 3);
    bf16x4 phi = __builtin_shufflevector(pack, pack, 4, 5, 6, 7);
    *(bf16x4*)(vbf + e1)       = plo;
    *(bf16x4*)(vbf + e1 + 128) = phi;
}

// ---------------------------------------------------------------------------
// Kernel 2: attention. ROUND 18: BG = 8 -> grid = 512 = qb(64) x bg(8);
// block = 128 q-rows x 1024 keys (32 chunks); 32 q-rows/wave (u=2).
// Halves Opart (16->8 MB) and the attn store count; r16/r17 proved
// {2,4} blocks/CU and {32,64} rows/wave are all perf-equivalent, so the
// doubled per-block key count costs nothing. LDS-staged K/V, double
// buffered, lgkmcnt-only barriers, setprio around MFMA cluster. No
// softmax denominator (l2norm cancels it).
#define STAGE_W(BUF, KR, VR) do {                                            \
        *(float4*)((BUF) + stb) = KR;                                        \
        *(float4*)((BUF) + 4096 + stb) = VR; } while (0)
#define STAGE_L(KR, VR) do {                                                 \
        KR = *(const float4*)gk; VR = *(const float4*)gv;                    \
        gk += 4096; gv += 4096; } while (0)

#define BARRIER_KEEP_VMCNT() do {                                            \
        asm volatile("s_waitcnt lgkmcnt(0)" ::: "memory");                   \
        __builtin_amdgcn_s_barrier(); } while (0)

#define COMPUTE(BUF) do {                                                    \
    const char* kbp = (BUF);                                                 \
    const char* vbp = (BUF) + 4096;                                          \
    bf16x8 k00 = *(const bf16x8*)(kbp + lb);                                 \
    bf16x8 k01 = *(const bf16x8*)(kbp + lb + 1024);                          \
    bf16x8 k10 = *(const bf16x8*)(kbp + lb + 2048);                          \
    bf16x8 k11 = *(const bf16x8*)(kbp + lb + 3072);                          \
    s16x8 W0 = *(const s16x8*)(vbp + lb);                                    \
    s16x8 W1 = *(const s16x8*)(vbp + lb + 1024);                             \
    s16x8 W2 = *(const s16x8*)(vbp + lb + 2048);                             \
    s16x8 W3 = *(const s16x8*)(vbp + lb + 3072);                             \
    const f32x4 zero = (f32x4){0.f, 0.f, 0.f, 0.f};                          \
    __builtin_amdgcn_s_setprio(1);                                           \
    _Pragma("unroll")                                                        \
    for (int u = 0; u < 2; ++u) {                                            \
        f32x4 s0 = mfma16(k00, qf32[u][0], zero);                            \
        s0       = mfma16(k01, qf32[u][1], s0);                              \
        f32x4 s1 = mfma16(k10, qf32[u][0], zero);                            \
        s1       = mfma16(k11, qf32[u][1], s1);                              \
        union { bf16x4 v; s16x4 s; } pf0, pf1;                               \
        _Pragma("unroll")                                                    \
        for (int r = 0; r < 4; ++r) {                                        \
            pf0.v[r] = (__bf16)__builtin_amdgcn_exp2f(s0[r]);                \
            pf1.v[r] = (__bf16)__builtin_amdgcn_exp2f(s1[r]);                \
        }                                                                    \
        of[u][0] = mfma1k(pf0.s, vlo(W0), of[u][0]);                         \
        of[u][0] = mfma1k(pf1.s, vlo(W2), of[u][0]);                         \
        of[u][1] = mfma1k(pf0.s, vhi(W0), of[u][1]);                         \
        of[u][1] = mfma1k(pf1.s, vhi(W2), of[u][1]);                         \
        of[u][2] = mfma1k(pf0.s, vlo(W1), of[u][2]);                         \
        of[u][2] = mfma1k(pf1.s, vlo(W3), of[u][2]);                         \
        of[u][3] = mfma1k(pf0.s, vhi(W1), of[u][3]);                         \
        of[u][3] = mfma1k(pf1.s, vhi(W3), of[u][3]);                         \
    }                                                                        \
    __builtin_amdgcn_s_setprio(0);                                           \
    } while (0)

__global__ __launch_bounds__(256, 4) void attn_kernel(
    const __hip_bfloat16* __restrict__ qbf,
    const __hip_bfloat16* __restrict__ kbf,
    const __hip_bfloat16* __restrict__ vbf,
    __hip_bfloat16* __restrict__ Opart,
    float* __restrict__ outz)
{
    __shared__ __align__(16) char pool[16384];
    char* bufA = pool;
    char* bufB = pool + 8192;

    const int tid = threadIdx.x;
    if (blockIdx.x == 0) {
        #pragma unroll
        for (int z = 0; z < 4; ++z)
            ((float4*)outz)[tid * 4 + z] = (float4){0.f, 0.f, 0.f, 0.f};
    }

    const int w    = tid >> 6;
    const int lane = tid & 63;
    const int l16  = lane & 15;
    const int quad = lane >> 4;
    const int qb   = blockIdx.x >> 3;                 // 0..63
    const int bg   = blockIdx.x & 7;                  // 0..7
    const int r0   = qb * 128 + w * 32;               // 32 q-rows per wave
    const int fo32 = l16 * 16 + (quad & 1) * 8;
    const int qh   = quad >> 1;
    const int lb   = lane * 16;
    const int stb  = tid * 16;

    bf16x8 qf32[2][2];
    #pragma unroll
    for (int u = 0; u < 2; ++u)
        #pragma unroll
        for (int p = 0; p < 2; ++p)
            qf32[u][p] = *(const bf16x8*)(qbf +
                ((((r0 >> 4) + u) * 4 + p * 2 + qh) << 8) + fo32);

    f32x4 of[2][4];
    #pragma unroll
    for (int u = 0; u < 2; ++u)
        #pragma unroll
        for (int n = 0; n < 4; ++n)
            of[u][n] = (f32x4){0.f, 0.f, 0.f, 0.f};

    // 32 chunks of 32 keys = 1024 keys per block
    const char* gk = (const char*)kbf + (size_t)(bg * 32) * 4096 + stb;
    const char* gv = (const char*)vbf + (size_t)(bg * 32) * 4096 + stb;

    float4 ka, va, kb_, vb_;
    STAGE_L(ka, va);
    STAGE_W(bufA, ka, va);
    STAGE_L(kb_, vb_);
    BARRIER_KEEP_VMCNT();                             // bufA ready

    #pragma unroll 1
    for (int body = 0; body < 15; ++body) {
        STAGE_W(bufB, kb_, vb_);
        STAGE_L(ka, va);
        COMPUTE(bufA);
        BARRIER_KEEP_VMCNT();
        STAGE_W(bufA, ka, va);
        STAGE_L(kb_, vb_);
        COMPUTE(bufB);
        BARRIER_KEEP_VMCNT();
    }
    STAGE_W(bufB, kb_, vb_);
    COMPUTE(bufA);
    BARRIER_KEEP_VMCNT();
    COMPUTE(bufB);

    // row-major-partials store: Opart[row][bg(8)][64] in BF16 (unnormalized)
    #pragma unroll
    for (int u = 0; u < 2; ++u)
        #pragma unroll
        for (int n = 0; n < 4; ++n)
            #pragma unroll
            for (int r = 0; r < 4; ++r)
                Opart[((size_t)(r0 + u * 16 + quad * 4 + r) * 8 + bg) * 64
                      + n * 16 + l16] = __float2bfloat16(of[u][n][r]);
}

// ---------------------------------------------------------------------------
// Kernel 3: FUSED combine + sim. grid = 256 blocks x 256 thr:
// block = (a, jhalf); a = bid>>1 is the contraction slice, jhalf = bid&1
// the 32-row half of Qn this block normalizes/multiplies. Phase 1: sum 8
// bf16 partials/row (one bf16x8 load per partial), l2-normalize (no lsum:
// cancels), bf16 -> LDS qn. Phase 2: 4 waves, K=64 folded in-register,
// atomicAdd into out (zeroed by attn block 0).
__global__ __launch_bounds__(256) void finish_kernel(
    const __hip_bfloat16* __restrict__ Opart,
    const __hip_bfloat16* __restrict__ vnb,
    float* __restrict__ out)
{
    __shared__ __hip_bfloat16 qn[32][68];

    const int a     = blockIdx.x >> 1;                // 0..127
    const int jhalf = blockIdx.x & 1;
    const int tid   = threadIdx.x;                    // 0..255

    // ---- phase 1: 8 threads per row (8 cols each), 32 rows ----
    {
        const int bl = tid >> 3;                      // 0..31 local row
        const int c8 = tid & 7;
        const int r  = (jhalf * 32 + bl) * 128 + a;
        float acc[8] = {0.f, 0.f, 0.f, 0.f, 0.f, 0.f, 0.f, 0.f};
        #pragma unroll
        for (int g = 0; g < 8; ++g) {
            bf16x8 t = *(const bf16x8*)(Opart +
                ((size_t)r * 8 + g) * 64 + c8 * 8);
            #pragma unroll
            for (int c = 0; c < 8; ++c)
                acc[c] += (float)t[c];
        }
        // no lsum: l2norm(O/l) == l2norm(O)
        float ss = 0.f;
        #pragma unroll
        for (int c = 0; c < 8; ++c)
            ss += acc[c] * acc[c];
        ss += __shfl_xor(ss, 1, 64);
        ss += __shfl_xor(ss, 2, 64);
        ss += __shfl_xor(ss, 4, 64);
        const float inv = rsqrtf(fmaxf(ss, 1e-24f));
        bf16x8 pk;
        #pragma unroll
        for (int c = 0; c < 8; ++c)
            pk[c] = (__bf16)(acc[c] * inv);
        *(bf16x8*)&qn[bl][c8 * 8] = pk;
    }
    __syncthreads();

    // ---- phase 2: GEMM, 4 waves = mi(4); K=64 folded in-register ----
    {
        const int w    = tid >> 6;                    // mi = 0..3
        const int lane = tid & 63;
        const int l16  = lane & 15;
        const int quad = lane >> 4;

        f32x4 accd[2];
        accd[0] = (f32x4){0.f, 0.f, 0.f, 0.f};
        accd[1] = (f32x4){0.f, 0.f, 0.f, 0.f};
        #pragma unroll
        for (int ks = 0; ks < 2; ++ks) {
            const int dq = ks * 32 + quad * 8;
            bf16x8 af = *(const bf16x8*)(vnb +
                (size_t)(w * 16 + l16) * 8192 + a * 64 + dq);
            #pragma unroll
            for (int ni = 0; ni < 2; ++ni) {
                bf16x8 bfv = *(const bf16x8*)&qn[ni * 16 + l16][dq];
                accd[ni] = mfma16(af, bfv, accd[ni]);
            }
        }
        #pragma unroll
        for (int ni = 0; ni < 2; ++ni)
            #pragma unroll
            for (int r = 0; r < 4; ++r)
                atomicAdd(&out[(w * 16 + quad * 4 + r) * 64 +
                               jhalf * 32 + ni * 16 + l16],
                          accd[ni][r] * (1.f / 128.f));
    }
}

// ---------------------------------------------------------------------------
extern "C" void kernel_launch(void* const* d_in, const int* in_sizes, int n_in,
                              void* d_out, int out_size, void* d_ws, size_t ws_size,
                              hipStream_t stream)
{
    const float* feat = (const float*)d_in[0];
    const float* Wq   = (const float*)d_in[1];
    const float* bq   = (const float*)d_in[2];
    const float* Wk   = (const float*)d_in[3];
    const float* bk   = (const float*)d_in[4];
    const float* Wv   = (const float*)d_in[5];
    const float* bv   = (const float*)d_in[6];
    float* out = (float*)d_out;

    const size_t MB = 1u << 20;
    char* ws = (char*)d_ws;
    __hip_bfloat16* qbf = (__hip_bfloat16*)(ws);              // 1 MB (frag-tiled, pre-scaled)
    __hip_bfloat16* kbf = (__hip_bfloat16*)(ws + 1 * MB);     // 1 MB (fragment-linear)
    __hip_bfloat16* vbf = (__hip_bfloat16*)(ws + 2 * MB);     // 1 MB (fragment-linear)
    __hip_bfloat16* vnb = (__hip_bfloat16*)(ws + 3 * MB);     // 1 MB (row-major)
    __hip_bfloat16* Opart = (__hip_bfloat16*)(ws + 4 * MB);   // 8 MB (8192 x 8 x 64 bf16)

    proj_kernel<<<256, 256, 0, stream>>>(feat, Wq, bq, Wk, bk, Wv, bv,
                                         qbf, kbf, vbf, vnb);
    attn_kernel<<<512, 256, 0, stream>>>(qbf, kbf, vbf, Opart, out);
    finish_kernel<<<256, 256, 0, stream>>>(Opart, vnb, out);
}